// Round 10
// baseline (501.911 us; speedup 1.0000x reference)
//
#include <hip/hip_runtime.h>

// GAT 3-layer forward on MI355X — round 22.
// R21 post-mortem: aggregate4 frozen at 62.5us (sj prefetch null). Two changes:
//  (1) gemm: R20's 2-barriers-per-ct loop drains vmcnt(0) 34x, exposing each ct's
//      B-prefetch latency. Now: round-based staging — RC cts per round staged into
//      double-buffered LDS via ASYNC global_load_lds (linear LDS dest, inverse-
//      swizzled GLOBAL source per rule #21), ONE barrier per round (6 vs 34 for
//      L1); round r+1's async loads issue right after the barrier and are covered
//      by round r's compute. Staging registers eliminated.
//  (2) aggregate4: double-buffer the 16 feat-row gathers (ucur/unx) — next chunk's
//      128B-row loads issue during this chunk's FMA phase (the el/sj prefetches
//      are already in place; the feat rows are the deep-latency loads). If this is
//      null, aggregate4 is at its L3->L2 gather roofline and gets frozen.

typedef __attribute__((ext_vector_type(8))) short s8v;
typedef __attribute__((ext_vector_type(4))) float f4v;
typedef __attribute__((ext_vector_type(2))) float f2v;
typedef __attribute__((ext_vector_type(2))) _Float16 h2;
typedef __attribute__((ext_vector_type(4))) _Float16 h4;

__device__ __forceinline__ unsigned short f2bf(float f) {
  unsigned int x = __float_as_uint(f);
  x += 0x7fffu + ((x >> 16) & 1u);          // RTNE
  return (unsigned short)(x >> 16);
}
__device__ __forceinline__ float bf2f(unsigned short u) {
  return __uint_as_float(((unsigned int)u) << 16);
}
__device__ __forceinline__ unsigned short f2h(float f) {
  _Float16 h = (_Float16)f;
  return __builtin_bit_cast(unsigned short, h);
}
__device__ __forceinline__ unsigned char f2fp8(float v) {
  return (unsigned char)(__builtin_amdgcn_cvt_pk_fp8_f32(v, v, 0, false) & 0xff);
}
__device__ __forceinline__ float lrelu(float x) { return fmaxf(x, 0.2f * x); }
__device__ __forceinline__ float elu1(float x) { return x > 0.f ? x : __expf(x) - 1.f; }

// ---------------- fused bucket histogram + weight pack (one launch) ----------------
__device__ __forceinline__ void pack_one(const float* W, const float* al, const float* ar,
                                         const float* resW, unsigned short* out,
                                         int K, int M, int BF, int H, int RES0, int t) {
  int c = t / K, k = t - c * K;
  float v = 0.f;
  if (c < BF) {
    v = W[k * BF + c];
  } else if (c < BF + H) {
    int h = c - BF;
    float s = 0.f;
    for (int d = 0; d < 32; d++) s += W[k * BF + h * 32 + d] * al[h * 32 + d];
    v = s;
  } else if (c < BF + 2 * H) {
    int h = c - BF - H;
    float s = 0.f;
    for (int d = 0; d < 32; d++) s += W[k * BF + h * 32 + d] * ar[h * 32 + d];
    v = s;
  } else if (c >= RES0) {
    v = resW[k * (M - RES0) + (c - RES0)];
  }
  unsigned short hi = f2bf(v);
  out[c * K + k] = hi;
  out[M * K + c * K + k] = f2bf(v - bf2f(hi));
}

__global__ __launch_bounds__(256) void hist_pack_k(const int* __restrict__ dst,
                                                   int* __restrict__ bhist, int E, int NB, int chunk, int P2B,
                                                   const float* __restrict__ W0, const float* __restrict__ al0,
                                                   const float* __restrict__ ar0,
                                                   const float* __restrict__ W1, const float* __restrict__ al1,
                                                   const float* __restrict__ ar1, const float* __restrict__ resW1,
                                                   const float* __restrict__ W2, const float* __restrict__ al2,
                                                   const float* __restrict__ ar2, const float* __restrict__ resW2,
                                                   unsigned short* __restrict__ w0t, unsigned short* __restrict__ w1t,
                                                   unsigned short* __restrict__ w2t) {
  if ((int)blockIdx.x < P2B) {
    __shared__ int h[512];
    for (int b = threadIdx.x; b < NB; b += 256) h[b] = 0;
    __syncthreads();
    int e0 = blockIdx.x * chunk;
    int e1 = min(E, e0 + chunk);
    int e = e0 + threadIdx.x * 4;
    for (; e + 3 < e1; e += 1024) {
      int4 d4 = *(const int4*)(dst + e);
      atomicAdd(&h[d4.x >> 8], 1);
      atomicAdd(&h[d4.y >> 8], 1);
      atomicAdd(&h[d4.z >> 8], 1);
      atomicAdd(&h[d4.w >> 8], 1);
    }
    for (; e < e1; e++) atomicAdd(&h[dst[e] >> 8], 1);
    __syncthreads();
    for (int b = threadIdx.x; b < NB; b += 256)
      bhist[(size_t)b * P2B + blockIdx.x] = h[b];
  } else {
    const int n0 = 144 * 64, n1 = 272 * 128, n2 = 80 * 128;
    int t = ((int)blockIdx.x - P2B) * 256 + threadIdx.x;
    if (t < n0) {
      pack_one(W0, al0, ar0, nullptr, w0t, 64, 144, 128, 4, 144, t);
    } else if (t < n0 + n1) {
      pack_one(W1, al1, ar1, resW1, w1t, 128, 272, 128, 4, 144, t - n0);
    } else if (t < n0 + n1 + n2) {
      pack_one(W2, al2, ar2, resW2, w2t, 128, 80, 32, 1, 48, t - n0 - n1);
    }
  }
}

// ---------------- bucket-segment table scan (phase 1 only; prefix re-derived later) --
__global__ __launch_bounds__(256) void pscan1(int* __restrict__ arr, int* __restrict__ bsum, int Nn) {
  __shared__ int s[256];
  int t = threadIdx.x;
  int base = blockIdx.x * 1024 + t * 4;
  int v0 = (base + 0 < Nn) ? arr[base + 0] : 0;
  int v1 = (base + 1 < Nn) ? arr[base + 1] : 0;
  int v2 = (base + 2 < Nn) ? arr[base + 2] : 0;
  int v3 = (base + 3 < Nn) ? arr[base + 3] : 0;
  s[t] = v0 + v1 + v2 + v3;
  __syncthreads();
  for (int off = 1; off < 256; off <<= 1) {
    int xv = (t >= off) ? s[t - off] : 0;
    __syncthreads();
    s[t] += xv;
    __syncthreads();
  }
  int excl = t ? s[t - 1] : 0;
  if (t == 255) bsum[blockIdx.x] = s[255];
  if (base + 0 < Nn) { arr[base + 0] = excl; excl += v0; }
  if (base + 1 < Nn) { arr[base + 1] = excl; excl += v1; }
  if (base + 2 < Nn) { arr[base + 2] = excl; excl += v2; }
  if (base + 3 < Nn) { arr[base + 3] = excl; }
}

// ---------------- pass 2: scatter edges into private (block,bucket) segments --------
__global__ __launch_bounds__(256) void bscatter_k(const int* __restrict__ src, const int* __restrict__ dst,
                                                  const int* __restrict__ bhist, const int* __restrict__ bsumB,
                                                  unsigned int* __restrict__ ebuf,
                                                  int E, int NB, int chunk, int nbB) {
  __shared__ int pref[256];
  __shared__ int cur[512];
  int t = threadIdx.x;
  pref[t] = (t < nbB) ? bsumB[t] : 0;
  __syncthreads();
  for (int off = 1; off < 256; off <<= 1) {
    int xv = (t >= off) ? pref[t - off] : 0;
    __syncthreads();
    pref[t] += xv;
    __syncthreads();
  }
  for (int b = t; b < NB; b += 256) {
    size_t idx = (size_t)b * gridDim.x + blockIdx.x;
    int sb = (int)(idx >> 10);
    cur[b] = bhist[idx] + (sb ? pref[sb - 1] : 0);
  }
  __syncthreads();
  int e0 = blockIdx.x * chunk;
  int e1 = min(E, e0 + chunk);
  int e = e0 + t * 4;
  for (; e + 3 < e1; e += 1024) {
    int4 d4 = *(const int4*)(dst + e);
    int4 s4 = *(const int4*)(src + e);
    int p0 = atomicAdd(&cur[d4.x >> 8], 1);
    ebuf[p0] = ((unsigned int)s4.x << 8) | (unsigned int)(d4.x & 255);
    int p1 = atomicAdd(&cur[d4.y >> 8], 1);
    ebuf[p1] = ((unsigned int)s4.y << 8) | (unsigned int)(d4.y & 255);
    int p2 = atomicAdd(&cur[d4.z >> 8], 1);
    ebuf[p2] = ((unsigned int)s4.z << 8) | (unsigned int)(d4.z & 255);
    int p3 = atomicAdd(&cur[d4.w >> 8], 1);
    ebuf[p3] = ((unsigned int)s4.w << 8) | (unsigned int)(d4.w & 255);
  }
  for (; e < e1; e++) {
    int d = dst[e];
    int pos = atomicAdd(&cur[d >> 8], 1);
    ebuf[pos] = ((unsigned int)src[e] << 8) | (unsigned int)(d & 255);
  }
}

// ---------------- pass 3: per-bucket final scatter + counts/rsp emission ------------
__global__ __launch_bounds__(256) void fscatter_k(const unsigned int* __restrict__ ebuf,
                                                  const int* __restrict__ bhist, const int* __restrict__ bsumB,
                                                  int* __restrict__ csr_src,
                                                  int* __restrict__ counts, int* __restrict__ rsp,
                                                  int E, int NB, int P2B, int Nn, int nbB) {
  __shared__ int pref[256];
  __shared__ int cnt[256];
  __shared__ int sc[256];
  __shared__ int cur[256];
  int b = blockIdx.x;
  int t = threadIdx.x;
  pref[t] = (t < nbB) ? bsumB[t] : 0;
  cnt[t] = 0;
  __syncthreads();
  for (int off = 1; off < 256; off <<= 1) {
    int xv = (t >= off) ? pref[t - off] : 0;
    __syncthreads();
    pref[t] += xv;
    __syncthreads();
  }
  size_t i1 = (size_t)b * P2B;
  int sb1 = (int)(i1 >> 10);
  int bstart = bhist[i1] + (sb1 ? pref[sb1 - 1] : 0);
  int bend = E;
  if (b + 1 < NB) {
    size_t i2 = (size_t)(b + 1) * P2B;
    int sb2 = (int)(i2 >> 10);
    bend = bhist[i2] + (sb2 ? pref[sb2 - 1] : 0);
  }
  for (int e = bstart + t; e < bend; e += 256)
    atomicAdd(&cnt[ebuf[e] & 255u], 1);
  __syncthreads();
  int v = cnt[t];
  sc[t] = v;
  __syncthreads();
  for (int off = 1; off < 256; off <<= 1) {
    int xv = (t >= off) ? sc[t - off] : 0;
    __syncthreads();
    sc[t] += xv;
    __syncthreads();
  }
  int base = bstart + (t ? sc[t - 1] : 0);
  int node = (b << 8) + t;
  if (node < Nn) { counts[node] = v; rsp[node] = base; }
  cur[t] = base;
  __syncthreads();
  for (int e = bstart + t; e < bend; e += 256) {
    unsigned int sd = ebuf[e];
    int pos = atomicAdd(&cur[sd & 255u], 1);
    csr_src[pos] = (int)(sd >> 8);
  }
}

// ---------------- cmw[col] = invN * colsum @ (W_hi + W_lo)  (rank-1 PairNorm fold) ----
__global__ __launch_bounds__(256) void cmw_k(const float* __restrict__ colsum,
                                             const unsigned short* __restrict__ wt,
                                             float* __restrict__ cmw, int K, int M, float invN) {
  int c = blockIdx.x * 256 + threadIdx.x;
  if (c >= M) return;
  float s = 0.f;
  for (int k = 0; k < K; k++)
    s += colsum[k] * (bf2f(wt[c * K + k]) + bf2f(wt[(size_t)M * K + c * K + k]));
  cmw[c] = s * invN;
}

// ---------------- GEMM: A[N,K] @ Bt[M,K](bf16 hi+lo), round-staged async LDS B ------
// RC cts per round, double-buffered; async global_load_lds (linear LDS dest,
// inverse-swizzled global source); ONE barrier per round.
template <int K, int M, int RC, int R, int BF, int H, int RES0, bool AF32, bool CMW>
__global__ __launch_bounds__(256) void gemm_bf16(const void* __restrict__ Av,
                                                 const unsigned short* __restrict__ Bt,
                                                 const float* __restrict__ cmw,
                                                 unsigned char* __restrict__ feat8,
                                                 float* __restrict__ el, float* __restrict__ er,
                                                 unsigned short* __restrict__ resh, int nRowTiles) {
  constexpr int NT = M / 16;            // column tiles
  constexpr int ROWB = K * 2;           // bytes per B row
  constexpr int PLANE = 16 * ROWB;      // bytes per ct per plane
  constexpr int PLANE2 = 2 * PLANE;     // hi+lo per ct
  constexpr int BUFSZ = RC * PLANE2;    // per round
  constexpr int NR = (NT + RC - 1) / RC;
  __shared__ __attribute__((aligned(16))) unsigned char buf[2 * BUFSZ];
  int t = threadIdx.x;
  int w = t >> 6;
  int lane = t & 63;
  int tile0 = (int)blockIdx.x * (4 * R) + w * R;
  int r = lane & 15, q = lane >> 4;

  // ---- A fragments (guarded per tile; invalid waves still barrier-loop) ----
  s8v afrag[R][K / 32];
  bool valid[R];
#pragma unroll
  for (int rr = 0; rr < R; rr++) {
    valid[rr] = (tile0 + rr) < nRowTiles;
    if (valid[rr]) {
      if constexpr (AF32) {
        const float* arow = (const float*)Av + (size_t)((tile0 + rr) * 16 + r) * K + q * 8;
#pragma unroll
        for (int kk = 0; kk < K / 32; kk++) {
          s8v v;
#pragma unroll
          for (int j = 0; j < 8; j++) v[j] = (short)f2bf(arow[kk * 32 + j]);
          afrag[rr][kk] = v;
        }
      } else {
        const unsigned short* arow = (const unsigned short*)Av + (size_t)((tile0 + rr) * 16 + r) * K + q * 8;
#pragma unroll
        for (int kk = 0; kk < K / 32; kk++) afrag[rr][kk] = *(const s8v*)(arow + kk * 32);
      }
    }
  }

  const unsigned char* gBhi = (const unsigned char*)Bt;
  const unsigned char* gBlo = gBhi + (size_t)M * K * 2;

  // async stage of round rr into buf half pb: linear LDS dest, inverse-swz source
  auto stage = [&](int rr, int pb) {
    int c0 = rr * RC;
    int nc = NT - c0;
    if (nc > RC) nc = RC;
    int bytes = nc * PLANE2;
    for (int off = t * 16; off < bytes; off += 4096) {
      int ctl = off / PLANE2;
      int rem = off - ctl * PLANE2;
      int pl = rem >= PLANE;
      int prem = pl ? rem - PLANE : rem;
      int row = prem / ROWB;
      int colb = prem - row * ROWB;
      int gcolb = colb ^ ((row & 7) << 4);
      const unsigned char* g = (pl ? gBlo : gBhi) + (size_t)(c0 + ctl) * PLANE + row * ROWB + gcolb;
      __builtin_amdgcn_global_load_lds(
          (const __attribute__((address_space(1))) void*)g,
          (__attribute__((address_space(3))) void*)(buf + pb * BUFSZ + off),
          16, 0, 0);
    }
  };

  stage(0, 0);
  for (int rr = 0; rr < NR; rr++) {
    int pb = rr & 1;
    __syncthreads();                        // buf[pb] staging complete
    if (rr + 1 < NR) stage(rr + 1, pb ^ 1); // async; covered by this round's compute
    int c0 = rr * RC;
    int ncts = NT - c0;
    if (ncts > RC) ncts = RC;
    for (int cl = 0; cl < ncts; cl++) {
      int ct = c0 + cl;
      const unsigned char* base = buf + pb * BUFSZ + cl * PLANE2;
      s8v bhi[K / 32], blo[K / 32];
#pragma unroll
      for (int kk = 0; kk < K / 32; kk++) {
        unsigned off = (unsigned)(q * 16 + kk * 64);
        unsigned ad = ((unsigned)r * ROWB) + (off ^ (((unsigned)(r & 7)) << 4));
        bhi[kk] = *(const s8v*)(base + ad);
        blo[kk] = *(const s8v*)(base + PLANE + ad);
      }
      int col = ct * 16 + r;
      float cmwv = 0.f;
      if constexpr (CMW) cmwv = cmw[col];
#pragma unroll
      for (int rr2 = 0; rr2 < R; rr2++) {
        if (!valid[rr2]) continue;
        f4v acc = {0.f, 0.f, 0.f, 0.f};
#pragma unroll
        for (int kk = 0; kk < K / 32; kk++) {
          acc = __builtin_amdgcn_mfma_f32_16x16x32_bf16(afrag[rr2][kk], bhi[kk], acc, 0, 0, 0);
          acc = __builtin_amdgcn_mfma_f32_16x16x32_bf16(afrag[rr2][kk], blo[kk], acc, 0, 0, 0);
        }
        int row0 = (tile0 + rr2) * 16 + q * 4;
#pragma unroll
        for (int i = 0; i < 4; i++) {
          float v = acc[i] - cmwv;
          size_t row = (size_t)(row0 + i);
          if (col < BF) {
            feat8[row * BF + col] = f2fp8(v);
          } else if (col < BF + H) {
            el[row * H + (col - BF)] = v;
          } else if (col < BF + 2 * H) {
            er[row * H + (col - BF - H)] = v;
          } else if (RES0 < M && col >= RES0) {
            resh[row * (M - RES0) + (col - RES0)] = f2h(v);
          }
        }
      }
    }
  }
}

// ---------------- fused single-pass aggregation H=4 (fp8 feat table) ----------------
// MLP=16 structure; el-gather, sj-batch AND feat-row loads all double-buffered:
// next chunk's 16 feat rows issue during this chunk's FMA phase.
template <int MODE>
__global__ __launch_bounds__(256) void aggregate4(const unsigned char* __restrict__ feat8,
                                                  const float* __restrict__ el4,
                                                  const float* __restrict__ er4,
                                                  const int* __restrict__ csr_src,
                                                  const int* __restrict__ rsp,
                                                  const int* __restrict__ counts,
                                                  const unsigned short* __restrict__ resh,
                                                  unsigned short* __restrict__ vbf,
                                                  float* __restrict__ rnrm, int Nn) {
  int n = (int)((blockIdx.x * blockDim.x + threadIdx.x) >> 6);
  if (n >= Nn) return;
  int lane = threadIdx.x & 63;
  int start = __builtin_amdgcn_readfirstlane(rsp[n]);
  int deg = __builtin_amdgcn_readfirstlane(counts[n]);
  int chunks = (deg + 15) >> 4;
  int slot = lane >> 2, h = lane & 3;
  float ern = er4[(size_t)n * 4 + h];
  int hl = lane >> 4;                        // head of lane's dims (dims 2l..2l+1)
  unsigned dby = (unsigned)lane << 1;        // byte offset into 128B fp8 row
  f2v a01 = {0.f, 0.f};
  float dsum = 0.f;
  // prologue: chunk 0's indices, el-gather, and feat rows
  const int* csp0 = csr_src + start;
  float elv = el4[(size_t)csp0[slot] * 4 + h];
  unsigned short ucur[16];
  {
    int sj0[16];
#pragma unroll
    for (int j = 0; j < 16; j++) sj0[j] = csp0[j];
#pragma unroll
    for (int j = 0; j < 16; j++)
      ucur[j] = *(const unsigned short*)(feat8 + (((unsigned)sj0[j] << 7) + dby));
  }
  for (int c = 0; c < chunks; c++) {
    float e = elv + ern;
    float exv = (((c << 4) + slot) < deg) ? __expf(fmaxf(e, 0.2f * e)) : 0.f;
    dsum += exv;
    // prefetch next chunk's indices + el + feat rows — in flight during FMAs
    unsigned short unx[16];
    bool more = (c + 1 < chunks);
    if (more) {
      const int* csp1 = csr_src + start + ((c + 1) << 4);
      int sjn[16];
#pragma unroll
      for (int j = 0; j < 16; j++) sjn[j] = csp1[j];
      elv = el4[(size_t)csp1[slot] * 4 + h];
#pragma unroll
      for (int j = 0; j < 16; j++)
        unx[j] = *(const unsigned short*)(feat8 + (((unsigned)sjn[j] << 7) + dby));
    }
#pragma unroll
    for (int j = 0; j < 16; j++) {
      float aw = __shfl(exv, (j << 2) | hl);
      f2v fv = __builtin_amdgcn_cvt_pk_f32_fp8((int)ucur[j], false);
      f2v aw2 = {aw, aw};
      a01 = __builtin_elementwise_fma(fv, aw2, a01);
    }
    if (more) {
#pragma unroll
      for (int j = 0; j < 16; j++) ucur[j] = unx[j];
    }
  }
#pragma unroll
  for (int off = 4; off < 64; off <<= 1) dsum += __shfl_xor(dsum, off);
  float inv = dsum > 0.f ? 1.f / dsum : 0.f;
  float invh = __shfl(inv, hl);
  float v0, v1;
  if (MODE == 1) {
    h2 rr = *(const h2*)(resh + (size_t)n * 128 + lane * 2);
    v0 = elu1(elu1(a01[0] * invh + (float)rr[0]));
    v1 = elu1(elu1(a01[1] * invh + (float)rr[1]));
  } else {
    v0 = elu1(a01[0] * invh);
    v1 = elu1(a01[1] * invh);
  }
  float ss = v0 * v0 + v1 * v1;
#pragma unroll
  for (int off = 1; off < 64; off <<= 1) ss += __shfl_xor(ss, off);
  float rn = sqrtf(1e-6f + ss);
  float ri = 1.f / rn;
  unsigned int pk = (unsigned int)f2bf(v0 * ri) | ((unsigned int)f2bf(v1 * ri) << 16);
  *(unsigned int*)((char*)vbf + ((size_t)n << 8) + (lane << 2)) = pk;
  if (lane == 0) rnrm[n] = rn;
}

// ---------------- fused single-pass aggregation H=1 (layer 2, fp8 table) ----------------
__global__ __launch_bounds__(256) void aggregate1(const unsigned char* __restrict__ feat8,
                                                  const float* __restrict__ el1,
                                                  const float* __restrict__ er1,
                                                  const int* __restrict__ csr_src,
                                                  const int* __restrict__ rsp,
                                                  const int* __restrict__ counts,
                                                  const unsigned short* __restrict__ res2h,
                                                  float* __restrict__ out2, int Nn) {
  int n = (int)((blockIdx.x * blockDim.x + threadIdx.x) >> 6);
  if (n >= Nn) return;
  int lane = threadIdx.x & 63;
  int start = __builtin_amdgcn_readfirstlane(rsp[n]);
  int deg = __builtin_amdgcn_readfirstlane(counts[n]);
  int chunks = (deg + 15) >> 4;
  int l16 = lane & 15;
  float ern = er1[n];
  int g = lane >> 3;                          // 8 edge groups (2 edges each per chunk)
  unsigned dofs4 = (unsigned)(lane & 7) << 2; // byte offset into 32B fp8 row
  f2v acc01 = {0.f, 0.f}, acc23 = {0.f, 0.f};
  float dsum = 0.f;
  int sA = csr_src[start + l16];
  float elv = el1[sA];
  for (int c = 0; c < chunks; c++) {
    const int* csp = csr_src + start + (c << 4);
    float exv = (((c << 4) + l16) < deg) ? __expf(lrelu(elv + ern)) : 0.f;
    dsum += exv;
    int sAc = sA;
    if (c + 1 < chunks) {
      sA = csp[16 + l16];
      elv = el1[sA];
    }
#pragma unroll
    for (int t = 0; t < 2; t++) {
      int j = (t << 3) + g;
      int sj = __shfl(sAc, j);
      float aw = __shfl(exv, j);
      f2v aw2 = {aw, aw};
      unsigned int u = *(const unsigned int*)(feat8 + (((unsigned)sj << 5) + dofs4));
      f2v fa = __builtin_amdgcn_cvt_pk_f32_fp8((int)u, false);
      f2v fb = __builtin_amdgcn_cvt_pk_f32_fp8((int)u, true);
      acc01 = __builtin_elementwise_fma(fa, aw2, acc01);
      acc23 = __builtin_elementwise_fma(fb, aw2, acc23);
    }
  }
#pragma unroll
  for (int off = 1; off < 16; off <<= 1) dsum += __shfl_xor(dsum, off);
  float inv = dsum > 0.f ? 1.f / dsum : 0.f;
#pragma unroll
  for (int off = 8; off < 64; off <<= 1) {
    acc01[0] += __shfl_xor(acc01[0], off);
    acc01[1] += __shfl_xor(acc01[1], off);
    acc23[0] += __shfl_xor(acc23[0], off);
    acc23[1] += __shfl_xor(acc23[1], off);
  }
  if (lane < 8) {
    h4 rr = *(const h4*)(res2h + (size_t)n * 32 + (lane << 2));
    float4 o;
    o.x = acc01[0] * inv + (float)rr[0];
    o.y = acc01[1] * inv + (float)rr[1];
    o.z = acc23[0] * inv + (float)rr[2];
    o.w = acc23[1] * inv + (float)rr[3];
    *(float4*)(out2 + (size_t)n * 32 + (lane << 2)) = o;
  }
}

// ---------------- colsum of raw v = vbf * rnrm (packed-uint loads) ----------------
__global__ __launch_bounds__(256) void colsum_k(const unsigned short* __restrict__ vbf,
                                                const float* __restrict__ rnrm,
                                                float* __restrict__ colsum, int Nn) {
  __shared__ float2 ls[256];
  int tid = threadIdx.x;
  int c2 = tid & 63;        // cols 2*c2, 2*c2+1
  int rsub = tid >> 6;      // 4 rows per iter
  float2 cs = {0.f, 0.f};
  for (int r = blockIdx.x * 4 + rsub; r < Nn; r += gridDim.x * 4) {
    unsigned u = *(const unsigned*)(vbf + (size_t)r * 128 + c2 * 2);
    float rn = rnrm[r];
    cs.x += bf2f((unsigned short)(u & 0xffffu)) * rn;
    cs.y += bf2f((unsigned short)(u >> 16)) * rn;
  }
  ls[tid] = cs;
  __syncthreads();
  if (tid < 64) {
    float2 a = ls[tid], b = ls[tid + 64], c = ls[tid + 128], d = ls[tid + 192];
    atomicAdd(&colsum[2 * tid], a.x + b.x + c.x + d.x);
    atomicAdd(&colsum[2 * tid + 1], a.y + b.y + c.y + d.y);
  }
}

// ---------------- final: mean over nodes of out2 ----------------
__global__ __launch_bounds__(256) void final_reduce(const float* __restrict__ out2,
                                                    float* __restrict__ outsum, int Nn) {
  __shared__ float ls[32];
  if (threadIdx.x < 32) ls[threadIdx.x] = 0.f;
  __syncthreads();
  int d = threadIdx.x & 31, rl = threadIdx.x >> 5;
  float acc = 0.f;
  for (int n = blockIdx.x * 8 + rl; n < Nn; n += gridDim.x * 8)
    acc += out2[(size_t)n * 32 + d];
  atomicAdd(&ls[d], acc);
  __syncthreads();
  if (threadIdx.x < 32) atomicAdd(&outsum[threadIdx.x], ls[threadIdx.x]);
}

__global__ void finalize_k(const float* __restrict__ outsum, float* __restrict__ out, float invN) {
  int t = threadIdx.x;
  if (t < 32) out[t] = outsum[t] * invN;
}

// ---------------- launcher ----------------
extern "C" void kernel_launch(void* const* d_in, const int* in_sizes, int n_in,
                              void* d_out, int out_size, void* d_ws, size_t ws_size,
                              hipStream_t stream) {
  const float* x     = (const float*)d_in[0];
  const int*   src   = (const int*)d_in[1];
  const int*   dst   = (const int*)d_in[2];
  const float* W0    = (const float*)d_in[3];
  const float* al0   = (const float*)d_in[4];
  const float* ar0   = (const float*)d_in[5];
  const float* W1    = (const float*)d_in[6];
  const float* al1   = (const float*)d_in[7];
  const float* ar1   = (const float*)d_in[8];
  const float* resW1 = (const float*)d_in[9];
  const float* W2    = (const float*)d_in[10];
  const float* al2   = (const float*)d_in[11];
  const float* ar2   = (const float*)d_in[12];
  const float* resW2 = (const float*)d_in[13];
  const int N = in_sizes[0] / 64;   // 100000
  const int E = in_sizes[1];        // 1600000
  const float invN = 1.f / (float)N;
  const int Emax = E + 64;              // unpadded CSR + zeroed tail guard
  const int NB = (N + 255) >> 8;        // dst buckets of 256 nodes (391)
  const int P2B = 512;                  // histogram/scatter block count
  const int chunk = (((E + P2B - 1) / P2B) + 3) & ~3;  // multiple of 4 for int4 loads
  const int segN = NB * P2B;            // bucket-major segment table length
  const int nbB = (segN + 1023) / 1024; // scan blocks for segment table (196)

  char* p = (char*)d_ws;
  auto alloc = [&](size_t bytes) { char* r = p; p += (bytes + 255) & ~(size_t)255; return r; };

  // zero-initialized region (small: reduction accumulators only)
  char* zbase = p;
  float* colsumA = (float*)alloc(512);
  float* colsumB = (float*)alloc(512);
  float* outsum  = (float*)alloc(128);
  size_t zbytes = (size_t)(p - zbase);

  int* counts = (int*)alloc((size_t)4 * N);     // written by fscatter
  int* rsp    = (int*)alloc((size_t)4 * N);     // written by fscatter (unpadded row starts)
  int* bsumB  = (int*)alloc(1024);
  int* bhist  = (int*)alloc((size_t)4 * segN);  // per-(bucket,block) counts -> per-1024-block scan
  unsigned int* ebuf = (unsigned int*)alloc((size_t)4 * E);  // packed (src<<8)|(dst&255)
  int* csr_src = (int*)alloc((size_t)4 * Emax);
  unsigned char*  feat8 = (unsigned char*)alloc((size_t)N * 128);     // fp8 gather table
  unsigned short* vbf   = (unsigned short*)alloc((size_t)2 * N * 128);
  unsigned short* resh  = (unsigned short*)alloc((size_t)2 * N * 128);  // f16 residuals
  unsigned short* w0t = (unsigned short*)alloc((size_t)2 * 2 * 144 * 64);
  unsigned short* w1t = (unsigned short*)alloc((size_t)2 * 2 * 272 * 128);
  unsigned short* w2t = (unsigned short*)alloc((size_t)2 * 2 * 80 * 128);
  float* el4  = (float*)alloc((size_t)16 * N);
  float* er4  = (float*)alloc((size_t)16 * N);
  float* rnrm = (float*)alloc((size_t)4 * N);
  float* cmw1 = (float*)alloc(4 * 272);
  float* cmw2 = (float*)alloc(4 * 80);
  float* out2 = (float*)alloc((size_t)4 * N * 32);   // layer-2 output [N][32]

  hipMemsetAsync(zbase, 0, zbytes, stream);
  hipMemsetAsync(csr_src + E, 0, (size_t)4 * (Emax - E), stream);  // tail guard only

  // CSR build + weight pack
  const int packTot = 144 * 64 + 272 * 128 + 80 * 128;   // 54272
  const int packBlocks = (packTot + 255) / 256;          // 212
  hist_pack_k<<<P2B + packBlocks, 256, 0, stream>>>(dst, bhist, E, NB, chunk, P2B,
                                                    W0, al0, ar0, W1, al1, ar1, resW1,
                                                    W2, al2, ar2, resW2, w0t, w1t, w2t);
  pscan1<<<nbB, 256, 0, stream>>>(bhist, bsumB, segN);
  bscatter_k<<<P2B, 256, 0, stream>>>(src, dst, bhist, bsumB, ebuf, E, NB, chunk, nbB);
  fscatter_k<<<NB, 256, 0, stream>>>(ebuf, bhist, bsumB, csr_src, counts, rsp, E, NB, P2B, N, nbB);

  const int rowTiles = N / 16;                   // 6250
  const int gblocks = (rowTiles + 7) / 8;        // 4 waves x R=2 tiles = 8 tiles/block
  const int aggblocks = (N + 3) / 4;             // wave per node

  // Layer 0 (A = x fp32, no colmean fold); K=64: RC=4 -> 32KB LDS, NR=3
  gemm_bf16<64, 144, 4, 2, 128, 4, 144, true, false><<<gblocks, 256, 0, stream>>>(
      x, w0t, nullptr, feat8, el4, er4, nullptr, rowTiles);
  aggregate4<0><<<aggblocks, 256, 0, stream>>>(feat8, el4, er4, csr_src, rsp, counts, nullptr, vbf, rnrm, N);
  colsum_k<<<512, 256, 0, stream>>>(vbf, rnrm, colsumA, N);
  cmw_k<<<2, 256, 0, stream>>>(colsumA, w1t, cmw1, 128, 272, invN);

  // Layer 1 (A = vbf, colmean via cmw1); K=128: RC=3 -> 48KB LDS, NR=6
  gemm_bf16<128, 272, 3, 2, 128, 4, 144, false, true><<<gblocks, 256, 0, stream>>>(
      vbf, w1t, cmw1, feat8, el4, er4, resh, rowTiles);
  aggregate4<1><<<aggblocks, 256, 0, stream>>>(feat8, el4, er4, csr_src, rsp, counts, resh, vbf, rnrm, N);
  colsum_k<<<512, 256, 0, stream>>>(vbf, rnrm, colsumB, N);
  cmw_k<<<1, 256, 0, stream>>>(colsumB, w2t, cmw2, 128, 80, invN);

  // Layer 2 (A = vbf, colmean via cmw2); K=128: RC=3, NR=2
  gemm_bf16<128, 80, 3, 2, 32, 1, 48, false, true><<<gblocks, 256, 0, stream>>>(
      vbf, w2t, cmw2, feat8, el4, er4, resh, rowTiles);
  aggregate1<<<aggblocks, 256, 0, stream>>>(feat8, el4, er4, csr_src, rsp, counts, resh, out2, N);
  final_reduce<<<512, 256, 0, stream>>>(out2, outsum, N);
  finalize_k<<<1, 64, 0, stream>>>(outsum, (float*)d_out, invN);
}

// Round 11
// 484.439 us; speedup vs baseline: 1.0361x; 1.0361x over previous
//
#include <hip/hip_runtime.h>

// GAT 3-layer forward on MI355X — round 23.
// R22 post-mortem: BOTH changes regressed (501.9 vs 476.6). (a) async-LDS gemm:
// 48KB dbuf LDS cut occupancy ~8->3 blocks/CU — TLP loss > barrier-drain savings
// (m132 lesson). (b) aggregate4 feat double-buffer: +4MB FETCH, +3us. Third null
// prefetch attempt on aggregate4 -> it is AT its random-gather pattern roofline
// (2.78 TB/s, 2 lines/edge); FROZEN at the R21 form. gemm reverted to R20 form
// (reg-staged prefetch, 2 barriers/ct, 16KB LDS, 8 blocks/CU).
// New (small, independent): final_reduce fused into aggregate1 — grid-stride at
// device residency (2048 blocks = 8192 waves), per-node outputs accumulated in
// registers, block LDS reduce, 32 atomics/block. Removes out2 (12.8MB write +
// 12.8MB read) and one launch.

typedef __attribute__((ext_vector_type(8))) short s8v;
typedef __attribute__((ext_vector_type(4))) float f4v;
typedef __attribute__((ext_vector_type(2))) float f2v;
typedef __attribute__((ext_vector_type(2))) _Float16 h2;
typedef __attribute__((ext_vector_type(4))) _Float16 h4;

__device__ __forceinline__ unsigned short f2bf(float f) {
  unsigned int x = __float_as_uint(f);
  x += 0x7fffu + ((x >> 16) & 1u);          // RTNE
  return (unsigned short)(x >> 16);
}
__device__ __forceinline__ float bf2f(unsigned short u) {
  return __uint_as_float(((unsigned int)u) << 16);
}
__device__ __forceinline__ unsigned short f2h(float f) {
  _Float16 h = (_Float16)f;
  return __builtin_bit_cast(unsigned short, h);
}
__device__ __forceinline__ unsigned char f2fp8(float v) {
  return (unsigned char)(__builtin_amdgcn_cvt_pk_fp8_f32(v, v, 0, false) & 0xff);
}
__device__ __forceinline__ float lrelu(float x) { return fmaxf(x, 0.2f * x); }
__device__ __forceinline__ float elu1(float x) { return x > 0.f ? x : __expf(x) - 1.f; }

// ---------------- fused bucket histogram + weight pack (one launch) ----------------
__device__ __forceinline__ void pack_one(const float* W, const float* al, const float* ar,
                                         const float* resW, unsigned short* out,
                                         int K, int M, int BF, int H, int RES0, int t) {
  int c = t / K, k = t - c * K;
  float v = 0.f;
  if (c < BF) {
    v = W[k * BF + c];
  } else if (c < BF + H) {
    int h = c - BF;
    float s = 0.f;
    for (int d = 0; d < 32; d++) s += W[k * BF + h * 32 + d] * al[h * 32 + d];
    v = s;
  } else if (c < BF + 2 * H) {
    int h = c - BF - H;
    float s = 0.f;
    for (int d = 0; d < 32; d++) s += W[k * BF + h * 32 + d] * ar[h * 32 + d];
    v = s;
  } else if (c >= RES0) {
    v = resW[k * (M - RES0) + (c - RES0)];
  }
  unsigned short hi = f2bf(v);
  out[c * K + k] = hi;
  out[M * K + c * K + k] = f2bf(v - bf2f(hi));
}

__global__ __launch_bounds__(256) void hist_pack_k(const int* __restrict__ dst,
                                                   int* __restrict__ bhist, int E, int NB, int chunk, int P2B,
                                                   const float* __restrict__ W0, const float* __restrict__ al0,
                                                   const float* __restrict__ ar0,
                                                   const float* __restrict__ W1, const float* __restrict__ al1,
                                                   const float* __restrict__ ar1, const float* __restrict__ resW1,
                                                   const float* __restrict__ W2, const float* __restrict__ al2,
                                                   const float* __restrict__ ar2, const float* __restrict__ resW2,
                                                   unsigned short* __restrict__ w0t, unsigned short* __restrict__ w1t,
                                                   unsigned short* __restrict__ w2t) {
  if ((int)blockIdx.x < P2B) {
    __shared__ int h[512];
    for (int b = threadIdx.x; b < NB; b += 256) h[b] = 0;
    __syncthreads();
    int e0 = blockIdx.x * chunk;
    int e1 = min(E, e0 + chunk);
    int e = e0 + threadIdx.x * 4;
    for (; e + 3 < e1; e += 1024) {
      int4 d4 = *(const int4*)(dst + e);
      atomicAdd(&h[d4.x >> 8], 1);
      atomicAdd(&h[d4.y >> 8], 1);
      atomicAdd(&h[d4.z >> 8], 1);
      atomicAdd(&h[d4.w >> 8], 1);
    }
    for (; e < e1; e++) atomicAdd(&h[dst[e] >> 8], 1);
    __syncthreads();
    for (int b = threadIdx.x; b < NB; b += 256)
      bhist[(size_t)b * P2B + blockIdx.x] = h[b];
  } else {
    const int n0 = 144 * 64, n1 = 272 * 128, n2 = 80 * 128;
    int t = ((int)blockIdx.x - P2B) * 256 + threadIdx.x;
    if (t < n0) {
      pack_one(W0, al0, ar0, nullptr, w0t, 64, 144, 128, 4, 144, t);
    } else if (t < n0 + n1) {
      pack_one(W1, al1, ar1, resW1, w1t, 128, 272, 128, 4, 144, t - n0);
    } else if (t < n0 + n1 + n2) {
      pack_one(W2, al2, ar2, resW2, w2t, 128, 80, 32, 1, 48, t - n0 - n1);
    }
  }
}

// ---------------- bucket-segment table scan (phase 1 only; prefix re-derived later) --
__global__ __launch_bounds__(256) void pscan1(int* __restrict__ arr, int* __restrict__ bsum, int Nn) {
  __shared__ int s[256];
  int t = threadIdx.x;
  int base = blockIdx.x * 1024 + t * 4;
  int v0 = (base + 0 < Nn) ? arr[base + 0] : 0;
  int v1 = (base + 1 < Nn) ? arr[base + 1] : 0;
  int v2 = (base + 2 < Nn) ? arr[base + 2] : 0;
  int v3 = (base + 3 < Nn) ? arr[base + 3] : 0;
  s[t] = v0 + v1 + v2 + v3;
  __syncthreads();
  for (int off = 1; off < 256; off <<= 1) {
    int xv = (t >= off) ? s[t - off] : 0;
    __syncthreads();
    s[t] += xv;
    __syncthreads();
  }
  int excl = t ? s[t - 1] : 0;
  if (t == 255) bsum[blockIdx.x] = s[255];
  if (base + 0 < Nn) { arr[base + 0] = excl; excl += v0; }
  if (base + 1 < Nn) { arr[base + 1] = excl; excl += v1; }
  if (base + 2 < Nn) { arr[base + 2] = excl; excl += v2; }
  if (base + 3 < Nn) { arr[base + 3] = excl; }
}

// ---------------- pass 2: scatter edges into private (block,bucket) segments --------
__global__ __launch_bounds__(256) void bscatter_k(const int* __restrict__ src, const int* __restrict__ dst,
                                                  const int* __restrict__ bhist, const int* __restrict__ bsumB,
                                                  unsigned int* __restrict__ ebuf,
                                                  int E, int NB, int chunk, int nbB) {
  __shared__ int pref[256];
  __shared__ int cur[512];
  int t = threadIdx.x;
  pref[t] = (t < nbB) ? bsumB[t] : 0;
  __syncthreads();
  for (int off = 1; off < 256; off <<= 1) {
    int xv = (t >= off) ? pref[t - off] : 0;
    __syncthreads();
    pref[t] += xv;
    __syncthreads();
  }
  for (int b = t; b < NB; b += 256) {
    size_t idx = (size_t)b * gridDim.x + blockIdx.x;
    int sb = (int)(idx >> 10);
    cur[b] = bhist[idx] + (sb ? pref[sb - 1] : 0);
  }
  __syncthreads();
  int e0 = blockIdx.x * chunk;
  int e1 = min(E, e0 + chunk);
  int e = e0 + t * 4;
  for (; e + 3 < e1; e += 1024) {
    int4 d4 = *(const int4*)(dst + e);
    int4 s4 = *(const int4*)(src + e);
    int p0 = atomicAdd(&cur[d4.x >> 8], 1);
    ebuf[p0] = ((unsigned int)s4.x << 8) | (unsigned int)(d4.x & 255);
    int p1 = atomicAdd(&cur[d4.y >> 8], 1);
    ebuf[p1] = ((unsigned int)s4.y << 8) | (unsigned int)(d4.y & 255);
    int p2 = atomicAdd(&cur[d4.z >> 8], 1);
    ebuf[p2] = ((unsigned int)s4.z << 8) | (unsigned int)(d4.z & 255);
    int p3 = atomicAdd(&cur[d4.w >> 8], 1);
    ebuf[p3] = ((unsigned int)s4.w << 8) | (unsigned int)(d4.w & 255);
  }
  for (; e < e1; e++) {
    int d = dst[e];
    int pos = atomicAdd(&cur[d >> 8], 1);
    ebuf[pos] = ((unsigned int)src[e] << 8) | (unsigned int)(d & 255);
  }
}

// ---------------- pass 3: per-bucket final scatter + counts/rsp emission ------------
__global__ __launch_bounds__(256) void fscatter_k(const unsigned int* __restrict__ ebuf,
                                                  const int* __restrict__ bhist, const int* __restrict__ bsumB,
                                                  int* __restrict__ csr_src,
                                                  int* __restrict__ counts, int* __restrict__ rsp,
                                                  int E, int NB, int P2B, int Nn, int nbB) {
  __shared__ int pref[256];
  __shared__ int cnt[256];
  __shared__ int sc[256];
  __shared__ int cur[256];
  int b = blockIdx.x;
  int t = threadIdx.x;
  pref[t] = (t < nbB) ? bsumB[t] : 0;
  cnt[t] = 0;
  __syncthreads();
  for (int off = 1; off < 256; off <<= 1) {
    int xv = (t >= off) ? pref[t - off] : 0;
    __syncthreads();
    pref[t] += xv;
    __syncthreads();
  }
  size_t i1 = (size_t)b * P2B;
  int sb1 = (int)(i1 >> 10);
  int bstart = bhist[i1] + (sb1 ? pref[sb1 - 1] : 0);
  int bend = E;
  if (b + 1 < NB) {
    size_t i2 = (size_t)(b + 1) * P2B;
    int sb2 = (int)(i2 >> 10);
    bend = bhist[i2] + (sb2 ? pref[sb2 - 1] : 0);
  }
  for (int e = bstart + t; e < bend; e += 256)
    atomicAdd(&cnt[ebuf[e] & 255u], 1);
  __syncthreads();
  int v = cnt[t];
  sc[t] = v;
  __syncthreads();
  for (int off = 1; off < 256; off <<= 1) {
    int xv = (t >= off) ? sc[t - off] : 0;
    __syncthreads();
    sc[t] += xv;
    __syncthreads();
  }
  int base = bstart + (t ? sc[t - 1] : 0);
  int node = (b << 8) + t;
  if (node < Nn) { counts[node] = v; rsp[node] = base; }
  cur[t] = base;
  __syncthreads();
  for (int e = bstart + t; e < bend; e += 256) {
    unsigned int sd = ebuf[e];
    int pos = atomicAdd(&cur[sd & 255u], 1);
    csr_src[pos] = (int)(sd >> 8);
  }
}

// ---------------- cmw[col] = invN * colsum @ (W_hi + W_lo)  (rank-1 PairNorm fold) ----
__global__ __launch_bounds__(256) void cmw_k(const float* __restrict__ colsum,
                                             const unsigned short* __restrict__ wt,
                                             float* __restrict__ cmw, int K, int M, float invN) {
  int c = blockIdx.x * 256 + threadIdx.x;
  if (c >= M) return;
  float s = 0.f;
  for (int k = 0; k < K; k++)
    s += colsum[k] * (bf2f(wt[c * K + k]) + bf2f(wt[(size_t)M * K + c * K + k]));
  cmw[c] = s * invN;
}

// ---------------- GEMM: A[N,K] @ Bt[M,K](bf16 hi+lo), LDS-staged B (R20 form) -------
template <int K, int M, int R, int BF, int H, int RES0, bool AF32, bool CMW>
__global__ __launch_bounds__(256) void gemm_bf16(const void* __restrict__ Av,
                                                 const unsigned short* __restrict__ Bt,
                                                 const float* __restrict__ cmw,
                                                 unsigned char* __restrict__ feat8,
                                                 float* __restrict__ el, float* __restrict__ er,
                                                 unsigned short* __restrict__ resh, int nRowTiles) {
  constexpr int NT = M / 16;              // column tiles
  constexpr int PLANE = 16 * K * 2;       // bytes per B plane (4096 or 2048)
  constexpr int RS = (K == 128) ? 8 : 7;  // log2(row bytes) for swizzle
  __shared__ unsigned char bbuf[2 * PLANE];  // [hi | lo]
  int t = threadIdx.x;
  int w = t >> 6;
  int lane = t & 63;
  int tile0 = (int)blockIdx.x * (4 * R) + w * R;
  int r = lane & 15, q = lane >> 4;

  // ---- A fragments (guarded per tile; invalid waves still barrier-loop) ----
  s8v afrag[R][K / 32];
  bool valid[R];
#pragma unroll
  for (int rr = 0; rr < R; rr++) {
    valid[rr] = (tile0 + rr) < nRowTiles;
    if (valid[rr]) {
      if constexpr (AF32) {
        const float* arow = (const float*)Av + (size_t)((tile0 + rr) * 16 + r) * K + q * 8;
#pragma unroll
        for (int kk = 0; kk < K / 32; kk++) {
          s8v v;
#pragma unroll
          for (int j = 0; j < 8; j++) v[j] = (short)f2bf(arow[kk * 32 + j]);
          afrag[rr][kk] = v;
        }
      } else {
        const unsigned short* arow = (const unsigned short*)Av + (size_t)((tile0 + rr) * 16 + r) * K + q * 8;
#pragma unroll
        for (int kk = 0; kk < K / 32; kk++) afrag[rr][kk] = *(const s8v*)(arow + kk * 32);
      }
    }
  }

  const unsigned char* gBhi = (const unsigned char*)Bt;
  const unsigned char* gBlo = (const unsigned char*)Bt + (size_t)M * K * 2;

  // ---- B stage prologue: load ct=0 into regs ----
  uint4 rh = {0, 0, 0, 0}, rl = {0, 0, 0, 0};
  if constexpr (K == 128) {
    rh = *(const uint4*)(gBhi + (size_t)0 * PLANE + t * 16);
    rl = *(const uint4*)(gBlo + (size_t)0 * PLANE + t * 16);
  } else {
    if (t < 128) rh = *(const uint4*)(gBhi + t * 16);
    else         rl = *(const uint4*)(gBlo + (t - 128) * 16);
  }

  for (int ct = 0; ct < NT; ct++) {
    // write staged regs to LDS (swizzled: byte ^= ((row&7)<<4))
    if constexpr (K == 128) {
      unsigned x = (unsigned)t * 16;
      unsigned d = x ^ (((x >> RS) & 7u) << 4);
      *(uint4*)(bbuf + d) = rh;
      *(uint4*)(bbuf + PLANE + d) = rl;
    } else {
      if (t < 128) {
        unsigned x = (unsigned)t * 16;
        unsigned d = x ^ (((x >> RS) & 7u) << 4);
        *(uint4*)(bbuf + d) = rh;
      } else {
        unsigned x = (unsigned)(t - 128) * 16;
        unsigned d = x ^ (((x >> RS) & 7u) << 4);
        *(uint4*)(bbuf + PLANE + d) = rl;
      }
    }
    __syncthreads();
    // prefetch next ct's B into regs — hides global latency under compute
    if (ct + 1 < NT) {
      if constexpr (K == 128) {
        rh = *(const uint4*)(gBhi + (size_t)(ct + 1) * PLANE + t * 16);
        rl = *(const uint4*)(gBlo + (size_t)(ct + 1) * PLANE + t * 16);
      } else {
        if (t < 128) rh = *(const uint4*)(gBhi + (size_t)(ct + 1) * PLANE + t * 16);
        else         rl = *(const uint4*)(gBlo + (size_t)(ct + 1) * PLANE + (t - 128) * 16);
      }
    }
    // read B fragments from LDS (swizzled)
    s8v bhi[K / 32], blo[K / 32];
#pragma unroll
    for (int kk = 0; kk < K / 32; kk++) {
      unsigned off = (unsigned)(q * 16 + kk * 64);
      unsigned ad = ((unsigned)r << RS) + (off ^ (((unsigned)(r & 7)) << 4));
      bhi[kk] = *(const s8v*)(bbuf + ad);
      blo[kk] = *(const s8v*)(bbuf + PLANE + ad);
    }
    int col = ct * 16 + r;
    float cmwv = 0.f;
    if constexpr (CMW) cmwv = cmw[col];
#pragma unroll
    for (int rr = 0; rr < R; rr++) {
      if (!valid[rr]) continue;
      f4v acc = {0.f, 0.f, 0.f, 0.f};
#pragma unroll
      for (int kk = 0; kk < K / 32; kk++) {
        acc = __builtin_amdgcn_mfma_f32_16x16x32_bf16(afrag[rr][kk], bhi[kk], acc, 0, 0, 0);
        acc = __builtin_amdgcn_mfma_f32_16x16x32_bf16(afrag[rr][kk], blo[kk], acc, 0, 0, 0);
      }
      int row0 = (tile0 + rr) * 16 + q * 4;
#pragma unroll
      for (int i = 0; i < 4; i++) {
        float v = acc[i] - cmwv;
        size_t row = (size_t)(row0 + i);
        if (col < BF) {
          feat8[row * BF + col] = f2fp8(v);
        } else if (col < BF + H) {
          el[row * H + (col - BF)] = v;
        } else if (col < BF + 2 * H) {
          er[row * H + (col - BF - H)] = v;
        } else if (RES0 < M && col >= RES0) {
          resh[row * (M - RES0) + (col - RES0)] = f2h(v);
        }
      }
    }
    __syncthreads();   // all reads of bbuf done before next ct's ds_write
  }
}

// ---------------- fused single-pass aggregation H=4 (R21 form — FROZEN) -------------
template <int MODE>
__global__ __launch_bounds__(256) void aggregate4(const unsigned char* __restrict__ feat8,
                                                  const float* __restrict__ el4,
                                                  const float* __restrict__ er4,
                                                  const int* __restrict__ csr_src,
                                                  const int* __restrict__ rsp,
                                                  const int* __restrict__ counts,
                                                  const unsigned short* __restrict__ resh,
                                                  unsigned short* __restrict__ vbf,
                                                  float* __restrict__ rnrm, int Nn) {
  int n = (int)((blockIdx.x * blockDim.x + threadIdx.x) >> 6);
  if (n >= Nn) return;
  int lane = threadIdx.x & 63;
  int start = __builtin_amdgcn_readfirstlane(rsp[n]);
  int deg = __builtin_amdgcn_readfirstlane(counts[n]);
  int chunks = (deg + 15) >> 4;
  int slot = lane >> 2, h = lane & 3;
  float ern = er4[(size_t)n * 4 + h];
  int hl = lane >> 4;                        // head of lane's dims (dims 2l..2l+1)
  unsigned dby = (unsigned)lane << 1;        // byte offset into 128B fp8 row
  f2v a01 = {0.f, 0.f};
  float dsum = 0.f;
  // prologue: chunk 0's sj batch + phase-A gather
  const int* csp0 = csr_src + start;
  int sj[16];
#pragma unroll
  for (int j = 0; j < 16; j++) sj[j] = csp0[j];
  float elv = el4[(size_t)csp0[slot] * 4 + h];
  for (int c = 0; c < chunks; c++) {
    float e = elv + ern;
    float exv = (((c << 4) + slot) < deg) ? __expf(fmaxf(e, 0.2f * e)) : 0.f;
    dsum += exv;
    // prefetch next chunk's batch + gather — in flight during this chunk's FMAs
    int sjn[16];
    bool more = (c + 1 < chunks);
    if (more) {
      const int* csp1 = csr_src + start + ((c + 1) << 4);
#pragma unroll
      for (int j = 0; j < 16; j++) sjn[j] = csp1[j];
      elv = el4[(size_t)csp1[slot] * 4 + h];
    }
#pragma unroll
    for (int j = 0; j < 16; j++) {
      float aw = __shfl(exv, (j << 2) | hl);
      unsigned short u = *(const unsigned short*)(feat8 + (((unsigned)sj[j] << 7) + dby));
      f2v fv = __builtin_amdgcn_cvt_pk_f32_fp8((int)u, false);
      f2v aw2 = {aw, aw};
      a01 = __builtin_elementwise_fma(fv, aw2, a01);
    }
    if (more) {
#pragma unroll
      for (int j = 0; j < 16; j++) sj[j] = sjn[j];
    }
  }
#pragma unroll
  for (int off = 4; off < 64; off <<= 1) dsum += __shfl_xor(dsum, off);
  float inv = dsum > 0.f ? 1.f / dsum : 0.f;
  float invh = __shfl(inv, hl);
  float v0, v1;
  if (MODE == 1) {
    h2 rr = *(const h2*)(resh + (size_t)n * 128 + lane * 2);
    v0 = elu1(elu1(a01[0] * invh + (float)rr[0]));
    v1 = elu1(elu1(a01[1] * invh + (float)rr[1]));
  } else {
    v0 = elu1(a01[0] * invh);
    v1 = elu1(a01[1] * invh);
  }
  float ss = v0 * v0 + v1 * v1;
#pragma unroll
  for (int off = 1; off < 64; off <<= 1) ss += __shfl_xor(ss, off);
  float rn = sqrtf(1e-6f + ss);
  float ri = 1.f / rn;
  unsigned int pk = (unsigned int)f2bf(v0 * ri) | ((unsigned int)f2bf(v1 * ri) << 16);
  *(unsigned int*)((char*)vbf + ((size_t)n << 8) + (lane << 2)) = pk;
  if (lane == 0) rnrm[n] = rn;
}

// ---------------- aggregation H=1 + fused final node-mean reduction ----------------
// Grid-stride over nodes at device residency; per-node output accumulated in regs
// (lanes<8 hold dims 4l..4l+3); block LDS reduce -> 32 atomics per block.
__global__ __launch_bounds__(256) void aggregate1(const unsigned char* __restrict__ feat8,
                                                  const float* __restrict__ el1,
                                                  const float* __restrict__ er1,
                                                  const int* __restrict__ csr_src,
                                                  const int* __restrict__ rsp,
                                                  const int* __restrict__ counts,
                                                  const unsigned short* __restrict__ res2h,
                                                  float* __restrict__ outsum, int Nn) {
  __shared__ float4 ls[32];   // [wave][lane<8]
  int lane = threadIdx.x & 63;
  int w = threadIdx.x >> 6;
  int l16 = lane & 15;
  int g = lane >> 3;                          // 8 edge groups (2 edges each per chunk)
  unsigned dofs4 = (unsigned)(lane & 7) << 2; // byte offset into 32B fp8 row
  float4 osum = {0.f, 0.f, 0.f, 0.f};
  for (int n = (int)blockIdx.x * 4 + w; n < Nn; n += (int)gridDim.x * 4) {
    int start = __builtin_amdgcn_readfirstlane(rsp[n]);
    int deg = __builtin_amdgcn_readfirstlane(counts[n]);
    int chunks = (deg + 15) >> 4;
    float ern = er1[n];
    f2v acc01 = {0.f, 0.f}, acc23 = {0.f, 0.f};
    float dsum = 0.f;
    int sA = csr_src[start + l16];
    float elv = el1[sA];
    for (int c = 0; c < chunks; c++) {
      const int* csp = csr_src + start + (c << 4);
      float exv = (((c << 4) + l16) < deg) ? __expf(lrelu(elv + ern)) : 0.f;
      dsum += exv;
      int sAc = sA;
      if (c + 1 < chunks) {
        sA = csp[16 + l16];
        elv = el1[sA];
      }
#pragma unroll
      for (int t = 0; t < 2; t++) {
        int j = (t << 3) + g;
        int sj = __shfl(sAc, j);
        float aw = __shfl(exv, j);
        f2v aw2 = {aw, aw};
        unsigned int u = *(const unsigned int*)(feat8 + (((unsigned)sj << 5) + dofs4));
        f2v fa = __builtin_amdgcn_cvt_pk_f32_fp8((int)u, false);
        f2v fb = __builtin_amdgcn_cvt_pk_f32_fp8((int)u, true);
        acc01 = __builtin_elementwise_fma(fa, aw2, acc01);
        acc23 = __builtin_elementwise_fma(fb, aw2, acc23);
      }
    }
#pragma unroll
    for (int off = 1; off < 16; off <<= 1) dsum += __shfl_xor(dsum, off);
    float inv = dsum > 0.f ? 1.f / dsum : 0.f;
#pragma unroll
    for (int off = 8; off < 64; off <<= 1) {
      acc01[0] += __shfl_xor(acc01[0], off);
      acc01[1] += __shfl_xor(acc01[1], off);
      acc23[0] += __shfl_xor(acc23[0], off);
      acc23[1] += __shfl_xor(acc23[1], off);
    }
    if (lane < 8) {
      h4 rr = *(const h4*)(res2h + (size_t)n * 32 + (lane << 2));
      osum.x += acc01[0] * inv + (float)rr[0];
      osum.y += acc01[1] * inv + (float)rr[1];
      osum.z += acc23[0] * inv + (float)rr[2];
      osum.w += acc23[1] * inv + (float)rr[3];
    }
  }
  if (lane < 8) ls[w * 8 + lane] = osum;
  __syncthreads();
  if (threadIdx.x < 32) {
    int li = threadIdx.x >> 2, ci = threadIdx.x & 3;
    float s = 0.f;
#pragma unroll
    for (int w2 = 0; w2 < 4; w2++) {
      float4 v4 = ls[w2 * 8 + li];
      s += ci == 0 ? v4.x : ci == 1 ? v4.y : ci == 2 ? v4.z : v4.w;
    }
    atomicAdd(&outsum[threadIdx.x], s);
  }
}

// ---------------- colsum of raw v = vbf * rnrm (packed-uint loads) ----------------
__global__ __launch_bounds__(256) void colsum_k(const unsigned short* __restrict__ vbf,
                                                const float* __restrict__ rnrm,
                                                float* __restrict__ colsum, int Nn) {
  __shared__ float2 ls[256];
  int tid = threadIdx.x;
  int c2 = tid & 63;        // cols 2*c2, 2*c2+1
  int rsub = tid >> 6;      // 4 rows per iter
  float2 cs = {0.f, 0.f};
  for (int r = blockIdx.x * 4 + rsub; r < Nn; r += gridDim.x * 4) {
    unsigned u = *(const unsigned*)(vbf + (size_t)r * 128 + c2 * 2);
    float rn = rnrm[r];
    cs.x += bf2f((unsigned short)(u & 0xffffu)) * rn;
    cs.y += bf2f((unsigned short)(u >> 16)) * rn;
  }
  ls[tid] = cs;
  __syncthreads();
  if (tid < 64) {
    float2 a = ls[tid], b = ls[tid + 64], c = ls[tid + 128], d = ls[tid + 192];
    atomicAdd(&colsum[2 * tid], a.x + b.x + c.x + d.x);
    atomicAdd(&colsum[2 * tid + 1], a.y + b.y + c.y + d.y);
  }
}

__global__ void finalize_k(const float* __restrict__ outsum, float* __restrict__ out, float invN) {
  int t = threadIdx.x;
  if (t < 32) out[t] = outsum[t] * invN;
}

// ---------------- launcher ----------------
extern "C" void kernel_launch(void* const* d_in, const int* in_sizes, int n_in,
                              void* d_out, int out_size, void* d_ws, size_t ws_size,
                              hipStream_t stream) {
  const float* x     = (const float*)d_in[0];
  const int*   src   = (const int*)d_in[1];
  const int*   dst   = (const int*)d_in[2];
  const float* W0    = (const float*)d_in[3];
  const float* al0   = (const float*)d_in[4];
  const float* ar0   = (const float*)d_in[5];
  const float* W1    = (const float*)d_in[6];
  const float* al1   = (const float*)d_in[7];
  const float* ar1   = (const float*)d_in[8];
  const float* resW1 = (const float*)d_in[9];
  const float* W2    = (const float*)d_in[10];
  const float* al2   = (const float*)d_in[11];
  const float* ar2   = (const float*)d_in[12];
  const float* resW2 = (const float*)d_in[13];
  const int N = in_sizes[0] / 64;   // 100000
  const int E = in_sizes[1];        // 1600000
  const float invN = 1.f / (float)N;
  const int Emax = E + 64;              // unpadded CSR + zeroed tail guard
  const int NB = (N + 255) >> 8;        // dst buckets of 256 nodes (391)
  const int P2B = 512;                  // histogram/scatter block count
  const int chunk = (((E + P2B - 1) / P2B) + 3) & ~3;  // multiple of 4 for int4 loads
  const int segN = NB * P2B;            // bucket-major segment table length
  const int nbB = (segN + 1023) / 1024; // scan blocks for segment table (196)

  char* p = (char*)d_ws;
  auto alloc = [&](size_t bytes) { char* r = p; p += (bytes + 255) & ~(size_t)255; return r; };

  // zero-initialized region (small: reduction accumulators only)
  char* zbase = p;
  float* colsumA = (float*)alloc(512);
  float* colsumB = (float*)alloc(512);
  float* outsum  = (float*)alloc(128);
  size_t zbytes = (size_t)(p - zbase);

  int* counts = (int*)alloc((size_t)4 * N);     // written by fscatter
  int* rsp    = (int*)alloc((size_t)4 * N);     // written by fscatter (unpadded row starts)
  int* bsumB  = (int*)alloc(1024);
  int* bhist  = (int*)alloc((size_t)4 * segN);  // per-(bucket,block) counts -> per-1024-block scan
  unsigned int* ebuf = (unsigned int*)alloc((size_t)4 * E);  // packed (src<<8)|(dst&255)
  int* csr_src = (int*)alloc((size_t)4 * Emax);
  unsigned char*  feat8 = (unsigned char*)alloc((size_t)N * 128);     // fp8 gather table
  unsigned short* vbf   = (unsigned short*)alloc((size_t)2 * N * 128);
  unsigned short* resh  = (unsigned short*)alloc((size_t)2 * N * 128);  // f16 residuals
  unsigned short* w0t = (unsigned short*)alloc((size_t)2 * 2 * 144 * 64);
  unsigned short* w1t = (unsigned short*)alloc((size_t)2 * 2 * 272 * 128);
  unsigned short* w2t = (unsigned short*)alloc((size_t)2 * 2 * 80 * 128);
  float* el4  = (float*)alloc((size_t)16 * N);
  float* er4  = (float*)alloc((size_t)16 * N);
  float* rnrm = (float*)alloc((size_t)4 * N);
  float* cmw1 = (float*)alloc(4 * 272);
  float* cmw2 = (float*)alloc(4 * 80);

  hipMemsetAsync(zbase, 0, zbytes, stream);
  hipMemsetAsync(csr_src + E, 0, (size_t)4 * (Emax - E), stream);  // tail guard only

  // CSR build + weight pack
  const int packTot = 144 * 64 + 272 * 128 + 80 * 128;   // 54272
  const int packBlocks = (packTot + 255) / 256;          // 212
  hist_pack_k<<<P2B + packBlocks, 256, 0, stream>>>(dst, bhist, E, NB, chunk, P2B,
                                                    W0, al0, ar0, W1, al1, ar1, resW1,
                                                    W2, al2, ar2, resW2, w0t, w1t, w2t);
  pscan1<<<nbB, 256, 0, stream>>>(bhist, bsumB, segN);
  bscatter_k<<<P2B, 256, 0, stream>>>(src, dst, bhist, bsumB, ebuf, E, NB, chunk, nbB);
  fscatter_k<<<NB, 256, 0, stream>>>(ebuf, bhist, bsumB, csr_src, counts, rsp, E, NB, P2B, N, nbB);

  const int rowTiles = N / 16;                   // 6250
  const int gblocks = (rowTiles + 7) / 8;        // 4 waves x R=2 tiles = 8 tiles/block
  const int aggblocks = (N + 3) / 4;             // wave per node

  // Layer 0 (A = x fp32, no colmean fold)
  gemm_bf16<64, 144, 2, 128, 4, 144, true, false><<<gblocks, 256, 0, stream>>>(
      x, w0t, nullptr, feat8, el4, er4, nullptr, rowTiles);
  aggregate4<0><<<aggblocks, 256, 0, stream>>>(feat8, el4, er4, csr_src, rsp, counts, nullptr, vbf, rnrm, N);
  colsum_k<<<512, 256, 0, stream>>>(vbf, rnrm, colsumA, N);
  cmw_k<<<2, 256, 0, stream>>>(colsumA, w1t, cmw1, 128, 272, invN);

  // Layer 1 (A = vbf, colmean via cmw1)
  gemm_bf16<128, 272, 2, 128, 4, 144, false, true><<<gblocks, 256, 0, stream>>>(
      vbf, w1t, cmw1, feat8, el4, er4, resh, rowTiles);
  aggregate4<1><<<aggblocks, 256, 0, stream>>>(feat8, el4, er4, csr_src, rsp, counts, resh, vbf, rnrm, N);
  colsum_k<<<512, 256, 0, stream>>>(vbf, rnrm, colsumB, N);
  cmw_k<<<1, 256, 0, stream>>>(colsumB, w2t, cmw2, 128, 80, invN);

  // Layer 2 (A = vbf, colmean via cmw2); aggregate1 fuses the node-mean reduction
  gemm_bf16<128, 80, 2, 32, 1, 48, false, true><<<gblocks, 256, 0, stream>>>(
      vbf, w2t, cmw2, feat8, el4, er4, resh, rowTiles);
  aggregate1<<<2048, 256, 0, stream>>>(feat8, el4, er4, csr_src, rsp, counts, resh, outsum, N);
  finalize_k<<<1, 64, 0, stream>>>(outsum, (float*)d_out, invN);
}

// Round 12
// 478.754 us; speedup vs baseline: 1.0484x; 1.0119x over previous
//
#include <hip/hip_runtime.h>

// GAT 3-layer forward on MI355X — round 24.
// R23 post-mortem: aggregate1+final_reduce fusion cost ~8us (TLP 25K->8K waves
// outweighed 25MB traffic saved) -> REVERTED to R21 form. aggregate4 confirmed
// frozen at roofline (62.9us, 2.76 TB/s gather).
// New: for L0/L2 the whole B fits in LDS (36.8KB / 40KB, >=3 blocks/CU unchanged):
// stage ALL of B once via async global_load_lds (linear LDS dest + inverse-swizzled
// global source, R22-verified), overlap staging with A-frag loads, ONE barrier,
// then a barrier-free ct loop (vs 18/10 barrier drains). L1 (136KB) keeps the
// proven R20 two-barrier reg-staged form — R22 showed dbuf-LDS occupancy loss hurts.

typedef __attribute__((ext_vector_type(8))) short s8v;
typedef __attribute__((ext_vector_type(4))) float f4v;
typedef __attribute__((ext_vector_type(2))) float f2v;
typedef __attribute__((ext_vector_type(2))) _Float16 h2;
typedef __attribute__((ext_vector_type(4))) _Float16 h4;

__device__ __forceinline__ unsigned short f2bf(float f) {
  unsigned int x = __float_as_uint(f);
  x += 0x7fffu + ((x >> 16) & 1u);          // RTNE
  return (unsigned short)(x >> 16);
}
__device__ __forceinline__ float bf2f(unsigned short u) {
  return __uint_as_float(((unsigned int)u) << 16);
}
__device__ __forceinline__ unsigned short f2h(float f) {
  _Float16 h = (_Float16)f;
  return __builtin_bit_cast(unsigned short, h);
}
__device__ __forceinline__ unsigned char f2fp8(float v) {
  return (unsigned char)(__builtin_amdgcn_cvt_pk_fp8_f32(v, v, 0, false) & 0xff);
}
__device__ __forceinline__ float lrelu(float x) { return fmaxf(x, 0.2f * x); }
__device__ __forceinline__ float elu1(float x) { return x > 0.f ? x : __expf(x) - 1.f; }

// ---------------- fused bucket histogram + weight pack (one launch) ----------------
__device__ __forceinline__ void pack_one(const float* W, const float* al, const float* ar,
                                         const float* resW, unsigned short* out,
                                         int K, int M, int BF, int H, int RES0, int t) {
  int c = t / K, k = t - c * K;
  float v = 0.f;
  if (c < BF) {
    v = W[k * BF + c];
  } else if (c < BF + H) {
    int h = c - BF;
    float s = 0.f;
    for (int d = 0; d < 32; d++) s += W[k * BF + h * 32 + d] * al[h * 32 + d];
    v = s;
  } else if (c < BF + 2 * H) {
    int h = c - BF - H;
    float s = 0.f;
    for (int d = 0; d < 32; d++) s += W[k * BF + h * 32 + d] * ar[h * 32 + d];
    v = s;
  } else if (c >= RES0) {
    v = resW[k * (M - RES0) + (c - RES0)];
  }
  unsigned short hi = f2bf(v);
  out[c * K + k] = hi;
  out[M * K + c * K + k] = f2bf(v - bf2f(hi));
}

__global__ __launch_bounds__(256) void hist_pack_k(const int* __restrict__ dst,
                                                   int* __restrict__ bhist, int E, int NB, int chunk, int P2B,
                                                   const float* __restrict__ W0, const float* __restrict__ al0,
                                                   const float* __restrict__ ar0,
                                                   const float* __restrict__ W1, const float* __restrict__ al1,
                                                   const float* __restrict__ ar1, const float* __restrict__ resW1,
                                                   const float* __restrict__ W2, const float* __restrict__ al2,
                                                   const float* __restrict__ ar2, const float* __restrict__ resW2,
                                                   unsigned short* __restrict__ w0t, unsigned short* __restrict__ w1t,
                                                   unsigned short* __restrict__ w2t) {
  if ((int)blockIdx.x < P2B) {
    __shared__ int h[512];
    for (int b = threadIdx.x; b < NB; b += 256) h[b] = 0;
    __syncthreads();
    int e0 = blockIdx.x * chunk;
    int e1 = min(E, e0 + chunk);
    int e = e0 + threadIdx.x * 4;
    for (; e + 3 < e1; e += 1024) {
      int4 d4 = *(const int4*)(dst + e);
      atomicAdd(&h[d4.x >> 8], 1);
      atomicAdd(&h[d4.y >> 8], 1);
      atomicAdd(&h[d4.z >> 8], 1);
      atomicAdd(&h[d4.w >> 8], 1);
    }
    for (; e < e1; e++) atomicAdd(&h[dst[e] >> 8], 1);
    __syncthreads();
    for (int b = threadIdx.x; b < NB; b += 256)
      bhist[(size_t)b * P2B + blockIdx.x] = h[b];
  } else {
    const int n0 = 144 * 64, n1 = 272 * 128, n2 = 80 * 128;
    int t = ((int)blockIdx.x - P2B) * 256 + threadIdx.x;
    if (t < n0) {
      pack_one(W0, al0, ar0, nullptr, w0t, 64, 144, 128, 4, 144, t);
    } else if (t < n0 + n1) {
      pack_one(W1, al1, ar1, resW1, w1t, 128, 272, 128, 4, 144, t - n0);
    } else if (t < n0 + n1 + n2) {
      pack_one(W2, al2, ar2, resW2, w2t, 128, 80, 32, 1, 48, t - n0 - n1);
    }
  }
}

// ---------------- bucket-segment table scan (phase 1 only; prefix re-derived later) --
__global__ __launch_bounds__(256) void pscan1(int* __restrict__ arr, int* __restrict__ bsum, int Nn) {
  __shared__ int s[256];
  int t = threadIdx.x;
  int base = blockIdx.x * 1024 + t * 4;
  int v0 = (base + 0 < Nn) ? arr[base + 0] : 0;
  int v1 = (base + 1 < Nn) ? arr[base + 1] : 0;
  int v2 = (base + 2 < Nn) ? arr[base + 2] : 0;
  int v3 = (base + 3 < Nn) ? arr[base + 3] : 0;
  s[t] = v0 + v1 + v2 + v3;
  __syncthreads();
  for (int off = 1; off < 256; off <<= 1) {
    int xv = (t >= off) ? s[t - off] : 0;
    __syncthreads();
    s[t] += xv;
    __syncthreads();
  }
  int excl = t ? s[t - 1] : 0;
  if (t == 255) bsum[blockIdx.x] = s[255];
  if (base + 0 < Nn) { arr[base + 0] = excl; excl += v0; }
  if (base + 1 < Nn) { arr[base + 1] = excl; excl += v1; }
  if (base + 2 < Nn) { arr[base + 2] = excl; excl += v2; }
  if (base + 3 < Nn) { arr[base + 3] = excl; }
}

// ---------------- pass 2: scatter edges into private (block,bucket) segments --------
__global__ __launch_bounds__(256) void bscatter_k(const int* __restrict__ src, const int* __restrict__ dst,
                                                  const int* __restrict__ bhist, const int* __restrict__ bsumB,
                                                  unsigned int* __restrict__ ebuf,
                                                  int E, int NB, int chunk, int nbB) {
  __shared__ int pref[256];
  __shared__ int cur[512];
  int t = threadIdx.x;
  pref[t] = (t < nbB) ? bsumB[t] : 0;
  __syncthreads();
  for (int off = 1; off < 256; off <<= 1) {
    int xv = (t >= off) ? pref[t - off] : 0;
    __syncthreads();
    pref[t] += xv;
    __syncthreads();
  }
  for (int b = t; b < NB; b += 256) {
    size_t idx = (size_t)b * gridDim.x + blockIdx.x;
    int sb = (int)(idx >> 10);
    cur[b] = bhist[idx] + (sb ? pref[sb - 1] : 0);
  }
  __syncthreads();
  int e0 = blockIdx.x * chunk;
  int e1 = min(E, e0 + chunk);
  int e = e0 + t * 4;
  for (; e + 3 < e1; e += 1024) {
    int4 d4 = *(const int4*)(dst + e);
    int4 s4 = *(const int4*)(src + e);
    int p0 = atomicAdd(&cur[d4.x >> 8], 1);
    ebuf[p0] = ((unsigned int)s4.x << 8) | (unsigned int)(d4.x & 255);
    int p1 = atomicAdd(&cur[d4.y >> 8], 1);
    ebuf[p1] = ((unsigned int)s4.y << 8) | (unsigned int)(d4.y & 255);
    int p2 = atomicAdd(&cur[d4.z >> 8], 1);
    ebuf[p2] = ((unsigned int)s4.z << 8) | (unsigned int)(d4.z & 255);
    int p3 = atomicAdd(&cur[d4.w >> 8], 1);
    ebuf[p3] = ((unsigned int)s4.w << 8) | (unsigned int)(d4.w & 255);
  }
  for (; e < e1; e++) {
    int d = dst[e];
    int pos = atomicAdd(&cur[d >> 8], 1);
    ebuf[pos] = ((unsigned int)src[e] << 8) | (unsigned int)(d & 255);
  }
}

// ---------------- pass 3: per-bucket final scatter + counts/rsp emission ------------
__global__ __launch_bounds__(256) void fscatter_k(const unsigned int* __restrict__ ebuf,
                                                  const int* __restrict__ bhist, const int* __restrict__ bsumB,
                                                  int* __restrict__ csr_src,
                                                  int* __restrict__ counts, int* __restrict__ rsp,
                                                  int E, int NB, int P2B, int Nn, int nbB) {
  __shared__ int pref[256];
  __shared__ int cnt[256];
  __shared__ int sc[256];
  __shared__ int cur[256];
  int b = blockIdx.x;
  int t = threadIdx.x;
  pref[t] = (t < nbB) ? bsumB[t] : 0;
  cnt[t] = 0;
  __syncthreads();
  for (int off = 1; off < 256; off <<= 1) {
    int xv = (t >= off) ? pref[t - off] : 0;
    __syncthreads();
    pref[t] += xv;
    __syncthreads();
  }
  size_t i1 = (size_t)b * P2B;
  int sb1 = (int)(i1 >> 10);
  int bstart = bhist[i1] + (sb1 ? pref[sb1 - 1] : 0);
  int bend = E;
  if (b + 1 < NB) {
    size_t i2 = (size_t)(b + 1) * P2B;
    int sb2 = (int)(i2 >> 10);
    bend = bhist[i2] + (sb2 ? pref[sb2 - 1] : 0);
  }
  for (int e = bstart + t; e < bend; e += 256)
    atomicAdd(&cnt[ebuf[e] & 255u], 1);
  __syncthreads();
  int v = cnt[t];
  sc[t] = v;
  __syncthreads();
  for (int off = 1; off < 256; off <<= 1) {
    int xv = (t >= off) ? sc[t - off] : 0;
    __syncthreads();
    sc[t] += xv;
    __syncthreads();
  }
  int base = bstart + (t ? sc[t - 1] : 0);
  int node = (b << 8) + t;
  if (node < Nn) { counts[node] = v; rsp[node] = base; }
  cur[t] = base;
  __syncthreads();
  for (int e = bstart + t; e < bend; e += 256) {
    unsigned int sd = ebuf[e];
    int pos = atomicAdd(&cur[sd & 255u], 1);
    csr_src[pos] = (int)(sd >> 8);
  }
}

// ---------------- cmw[col] = invN * colsum @ (W_hi + W_lo)  (rank-1 PairNorm fold) ----
__global__ __launch_bounds__(256) void cmw_k(const float* __restrict__ colsum,
                                             const unsigned short* __restrict__ wt,
                                             float* __restrict__ cmw, int K, int M, float invN) {
  int c = blockIdx.x * 256 + threadIdx.x;
  if (c >= M) return;
  float s = 0.f;
  for (int k = 0; k < K; k++)
    s += colsum[k] * (bf2f(wt[c * K + k]) + bf2f(wt[(size_t)M * K + c * K + k]));
  cmw[c] = s * invN;
}

// ---------------- GEMM: A[N,K] @ Bt[M,K](bf16 hi+lo), LDS-staged B ----------------
// FULL=true (B fits in LDS): async-stage ALL of B once (overlapped with A-frag
// loads), one barrier, barrier-free ct loop. FULL=false: R20 two-barrier form.
template <int K, int M, int R, int BF, int H, int RES0, bool AF32, bool CMW, bool FULL>
__global__ __launch_bounds__(256) void gemm_bf16(const void* __restrict__ Av,
                                                 const unsigned short* __restrict__ Bt,
                                                 const float* __restrict__ cmw,
                                                 unsigned char* __restrict__ feat8,
                                                 float* __restrict__ el, float* __restrict__ er,
                                                 unsigned short* __restrict__ resh, int nRowTiles) {
  constexpr int NT = M / 16;              // column tiles
  constexpr int ROWB = K * 2;             // bytes per B row (col of W)
  constexpr int PLANE = 16 * ROWB;        // bytes per ct per plane
  constexpr int PLANE2 = 2 * PLANE;       // hi+lo per ct
  constexpr int RS = (K == 128) ? 8 : 7;  // log2(ROWB) for swizzle
  constexpr int LDSB = FULL ? NT * PLANE2 : 2 * PLANE;
  __shared__ __attribute__((aligned(16))) unsigned char bbuf[LDSB];
  int t = threadIdx.x;
  int w = t >> 6;
  int lane = t & 63;
  int tile0 = (int)blockIdx.x * (4 * R) + w * R;
  int r = lane & 15, q = lane >> 4;

  const unsigned char* gBhi = (const unsigned char*)Bt;
  const unsigned char* gBlo = gBhi + (size_t)M * K * 2;

  if constexpr (FULL) {
    // async stage of ALL of B: linear LDS dest, inverse-swizzled global source
    for (int off = t * 16; off < NT * PLANE2; off += 4096) {
      int ctl = off / PLANE2;
      int rem = off - ctl * PLANE2;
      int pl = rem >= PLANE;
      int prem = pl ? rem - PLANE : rem;
      int row = prem / ROWB;
      int colb = prem - row * ROWB;
      int gcolb = colb ^ ((row & 7) << 4);
      const unsigned char* g = (pl ? gBlo : gBhi) + (size_t)ctl * PLANE + row * ROWB + gcolb;
      __builtin_amdgcn_global_load_lds(
          (const __attribute__((address_space(1))) void*)g,
          (__attribute__((address_space(3))) void*)(bbuf + off), 16, 0, 0);
    }
  }

  // ---- A fragments (overlap with async B staging when FULL) ----
  s8v afrag[R][K / 32];
  bool valid[R];
#pragma unroll
  for (int rr = 0; rr < R; rr++) {
    valid[rr] = (tile0 + rr) < nRowTiles;
    if (valid[rr]) {
      if constexpr (AF32) {
        const float* arow = (const float*)Av + (size_t)((tile0 + rr) * 16 + r) * K + q * 8;
#pragma unroll
        for (int kk = 0; kk < K / 32; kk++) {
          s8v v;
#pragma unroll
          for (int j = 0; j < 8; j++) v[j] = (short)f2bf(arow[kk * 32 + j]);
          afrag[rr][kk] = v;
        }
      } else {
        const unsigned short* arow = (const unsigned short*)Av + (size_t)((tile0 + rr) * 16 + r) * K + q * 8;
#pragma unroll
        for (int kk = 0; kk < K / 32; kk++) afrag[rr][kk] = *(const s8v*)(arow + kk * 32);
      }
    }
  }

  // ---- non-FULL: B stage prologue (ct=0 into regs) ----
  uint4 rh = {0, 0, 0, 0}, rl = {0, 0, 0, 0};
  if constexpr (!FULL) {
    if constexpr (K == 128) {
      rh = *(const uint4*)(gBhi + t * 16);
      rl = *(const uint4*)(gBlo + t * 16);
    } else {
      if (t < 128) rh = *(const uint4*)(gBhi + t * 16);
      else         rl = *(const uint4*)(gBlo + (t - 128) * 16);
    }
  }

  if constexpr (FULL) __syncthreads();   // all B staged

  for (int ct = 0; ct < NT; ct++) {
    const unsigned char* base;
    if constexpr (FULL) {
      base = bbuf + ct * PLANE2;
    } else {
      // write staged regs to LDS (swizzled: byte ^= ((row&7)<<4))
      if constexpr (K == 128) {
        unsigned x = (unsigned)t * 16;
        unsigned d = x ^ (((x >> RS) & 7u) << 4);
        *(uint4*)(bbuf + d) = rh;
        *(uint4*)(bbuf + PLANE + d) = rl;
      } else {
        if (t < 128) {
          unsigned x = (unsigned)t * 16;
          unsigned d = x ^ (((x >> RS) & 7u) << 4);
          *(uint4*)(bbuf + d) = rh;
        } else {
          unsigned x = (unsigned)(t - 128) * 16;
          unsigned d = x ^ (((x >> RS) & 7u) << 4);
          *(uint4*)(bbuf + PLANE + d) = rl;
        }
      }
      __syncthreads();
      // prefetch next ct's B into regs
      if (ct + 1 < NT) {
        if constexpr (K == 128) {
          rh = *(const uint4*)(gBhi + (size_t)(ct + 1) * PLANE + t * 16);
          rl = *(const uint4*)(gBlo + (size_t)(ct + 1) * PLANE + t * 16);
        } else {
          if (t < 128) rh = *(const uint4*)(gBhi + (size_t)(ct + 1) * PLANE + t * 16);
          else         rl = *(const uint4*)(gBlo + (size_t)(ct + 1) * PLANE + (t - 128) * 16);
        }
      }
      base = bbuf;
    }
    // read B fragments from LDS (swizzled)
    s8v bhi[K / 32], blo[K / 32];
#pragma unroll
    for (int kk = 0; kk < K / 32; kk++) {
      unsigned off = (unsigned)(q * 16 + kk * 64);
      unsigned ad = ((unsigned)r << RS) + (off ^ (((unsigned)(r & 7)) << 4));
      bhi[kk] = *(const s8v*)(base + ad);
      blo[kk] = *(const s8v*)(base + PLANE + ad);
    }
    int col = ct * 16 + r;
    float cmwv = 0.f;
    if constexpr (CMW) cmwv = cmw[col];
#pragma unroll
    for (int rr = 0; rr < R; rr++) {
      if (!valid[rr]) continue;
      f4v acc = {0.f, 0.f, 0.f, 0.f};
#pragma unroll
      for (int kk = 0; kk < K / 32; kk++) {
        acc = __builtin_amdgcn_mfma_f32_16x16x32_bf16(afrag[rr][kk], bhi[kk], acc, 0, 0, 0);
        acc = __builtin_amdgcn_mfma_f32_16x16x32_bf16(afrag[rr][kk], blo[kk], acc, 0, 0, 0);
      }
      int row0 = (tile0 + rr) * 16 + q * 4;
#pragma unroll
      for (int i = 0; i < 4; i++) {
        float v = acc[i] - cmwv;
        size_t row = (size_t)(row0 + i);
        if (col < BF) {
          feat8[row * BF + col] = f2fp8(v);
        } else if (col < BF + H) {
          el[row * H + (col - BF)] = v;
        } else if (col < BF + 2 * H) {
          er[row * H + (col - BF - H)] = v;
        } else if (RES0 < M && col >= RES0) {
          resh[row * (M - RES0) + (col - RES0)] = f2h(v);
        }
      }
    }
    if constexpr (!FULL) __syncthreads();   // bbuf reads done before next ds_write
  }
}

// ---------------- fused single-pass aggregation H=4 (R21 form — FROZEN) -------------
template <int MODE>
__global__ __launch_bounds__(256) void aggregate4(const unsigned char* __restrict__ feat8,
                                                  const float* __restrict__ el4,
                                                  const float* __restrict__ er4,
                                                  const int* __restrict__ csr_src,
                                                  const int* __restrict__ rsp,
                                                  const int* __restrict__ counts,
                                                  const unsigned short* __restrict__ resh,
                                                  unsigned short* __restrict__ vbf,
                                                  float* __restrict__ rnrm, int Nn) {
  int n = (int)((blockIdx.x * blockDim.x + threadIdx.x) >> 6);
  if (n >= Nn) return;
  int lane = threadIdx.x & 63;
  int start = __builtin_amdgcn_readfirstlane(rsp[n]);
  int deg = __builtin_amdgcn_readfirstlane(counts[n]);
  int chunks = (deg + 15) >> 4;
  int slot = lane >> 2, h = lane & 3;
  float ern = er4[(size_t)n * 4 + h];
  int hl = lane >> 4;                        // head of lane's dims (dims 2l..2l+1)
  unsigned dby = (unsigned)lane << 1;        // byte offset into 128B fp8 row
  f2v a01 = {0.f, 0.f};
  float dsum = 0.f;
  // prologue: chunk 0's sj batch + phase-A gather
  const int* csp0 = csr_src + start;
  int sj[16];
#pragma unroll
  for (int j = 0; j < 16; j++) sj[j] = csp0[j];
  float elv = el4[(size_t)csp0[slot] * 4 + h];
  for (int c = 0; c < chunks; c++) {
    float e = elv + ern;
    float exv = (((c << 4) + slot) < deg) ? __expf(fmaxf(e, 0.2f * e)) : 0.f;
    dsum += exv;
    // prefetch next chunk's batch + gather — in flight during this chunk's FMAs
    int sjn[16];
    bool more = (c + 1 < chunks);
    if (more) {
      const int* csp1 = csr_src + start + ((c + 1) << 4);
#pragma unroll
      for (int j = 0; j < 16; j++) sjn[j] = csp1[j];
      elv = el4[(size_t)csp1[slot] * 4 + h];
    }
#pragma unroll
    for (int j = 0; j < 16; j++) {
      float aw = __shfl(exv, (j << 2) | hl);
      unsigned short u = *(const unsigned short*)(feat8 + (((unsigned)sj[j] << 7) + dby));
      f2v fv = __builtin_amdgcn_cvt_pk_f32_fp8((int)u, false);
      f2v aw2 = {aw, aw};
      a01 = __builtin_elementwise_fma(fv, aw2, a01);
    }
    if (more) {
#pragma unroll
      for (int j = 0; j < 16; j++) sj[j] = sjn[j];
    }
  }
#pragma unroll
  for (int off = 4; off < 64; off <<= 1) dsum += __shfl_xor(dsum, off);
  float inv = dsum > 0.f ? 1.f / dsum : 0.f;
  float invh = __shfl(inv, hl);
  float v0, v1;
  if (MODE == 1) {
    h2 rr = *(const h2*)(resh + (size_t)n * 128 + lane * 2);
    v0 = elu1(elu1(a01[0] * invh + (float)rr[0]));
    v1 = elu1(elu1(a01[1] * invh + (float)rr[1]));
  } else {
    v0 = elu1(a01[0] * invh);
    v1 = elu1(a01[1] * invh);
  }
  float ss = v0 * v0 + v1 * v1;
#pragma unroll
  for (int off = 1; off < 64; off <<= 1) ss += __shfl_xor(ss, off);
  float rn = sqrtf(1e-6f + ss);
  float ri = 1.f / rn;
  unsigned int pk = (unsigned int)f2bf(v0 * ri) | ((unsigned int)f2bf(v1 * ri) << 16);
  *(unsigned int*)((char*)vbf + ((size_t)n << 8) + (lane << 2)) = pk;
  if (lane == 0) rnrm[n] = rn;
}

// ---------------- fused single-pass aggregation H=1 (R21 form) ----------------
__global__ __launch_bounds__(256) void aggregate1(const unsigned char* __restrict__ feat8,
                                                  const float* __restrict__ el1,
                                                  const float* __restrict__ er1,
                                                  const int* __restrict__ csr_src,
                                                  const int* __restrict__ rsp,
                                                  const int* __restrict__ counts,
                                                  const unsigned short* __restrict__ res2h,
                                                  float* __restrict__ out2, int Nn) {
  int n = (int)((blockIdx.x * blockDim.x + threadIdx.x) >> 6);
  if (n >= Nn) return;
  int lane = threadIdx.x & 63;
  int start = __builtin_amdgcn_readfirstlane(rsp[n]);
  int deg = __builtin_amdgcn_readfirstlane(counts[n]);
  int chunks = (deg + 15) >> 4;
  int l16 = lane & 15;
  float ern = er1[n];
  int g = lane >> 3;                          // 8 edge groups (2 edges each per chunk)
  unsigned dofs4 = (unsigned)(lane & 7) << 2; // byte offset into 32B fp8 row
  f2v acc01 = {0.f, 0.f}, acc23 = {0.f, 0.f};
  float dsum = 0.f;
  int sA = csr_src[start + l16];
  float elv = el1[sA];
  for (int c = 0; c < chunks; c++) {
    const int* csp = csr_src + start + (c << 4);
    float exv = (((c << 4) + l16) < deg) ? __expf(lrelu(elv + ern)) : 0.f;
    dsum += exv;
    int sAc = sA;
    if (c + 1 < chunks) {
      sA = csp[16 + l16];
      elv = el1[sA];
    }
#pragma unroll
    for (int t = 0; t < 2; t++) {
      int j = (t << 3) + g;
      int sj = __shfl(sAc, j);
      float aw = __shfl(exv, j);
      f2v aw2 = {aw, aw};
      unsigned int u = *(const unsigned int*)(feat8 + (((unsigned)sj << 5) + dofs4));
      f2v fa = __builtin_amdgcn_cvt_pk_f32_fp8((int)u, false);
      f2v fb = __builtin_amdgcn_cvt_pk_f32_fp8((int)u, true);
      acc01 = __builtin_elementwise_fma(fa, aw2, acc01);
      acc23 = __builtin_elementwise_fma(fb, aw2, acc23);
    }
  }
#pragma unroll
  for (int off = 1; off < 16; off <<= 1) dsum += __shfl_xor(dsum, off);
  float inv = dsum > 0.f ? 1.f / dsum : 0.f;
#pragma unroll
  for (int off = 8; off < 64; off <<= 1) {
    acc01[0] += __shfl_xor(acc01[0], off);
    acc01[1] += __shfl_xor(acc01[1], off);
    acc23[0] += __shfl_xor(acc23[0], off);
    acc23[1] += __shfl_xor(acc23[1], off);
  }
  if (lane < 8) {
    h4 rr = *(const h4*)(res2h + (size_t)n * 32 + (lane << 2));
    float4 o;
    o.x = acc01[0] * inv + (float)rr[0];
    o.y = acc01[1] * inv + (float)rr[1];
    o.z = acc23[0] * inv + (float)rr[2];
    o.w = acc23[1] * inv + (float)rr[3];
    *(float4*)(out2 + (size_t)n * 32 + (lane << 2)) = o;
  }
}

// ---------------- colsum of raw v = vbf * rnrm (packed-uint loads) ----------------
__global__ __launch_bounds__(256) void colsum_k(const unsigned short* __restrict__ vbf,
                                                const float* __restrict__ rnrm,
                                                float* __restrict__ colsum, int Nn) {
  __shared__ float2 ls[256];
  int tid = threadIdx.x;
  int c2 = tid & 63;        // cols 2*c2, 2*c2+1
  int rsub = tid >> 6;      // 4 rows per iter
  float2 cs = {0.f, 0.f};
  for (int r = blockIdx.x * 4 + rsub; r < Nn; r += gridDim.x * 4) {
    unsigned u = *(const unsigned*)(vbf + (size_t)r * 128 + c2 * 2);
    float rn = rnrm[r];
    cs.x += bf2f((unsigned short)(u & 0xffffu)) * rn;
    cs.y += bf2f((unsigned short)(u >> 16)) * rn;
  }
  ls[tid] = cs;
  __syncthreads();
  if (tid < 64) {
    float2 a = ls[tid], b = ls[tid + 64], c = ls[tid + 128], d = ls[tid + 192];
    atomicAdd(&colsum[2 * tid], a.x + b.x + c.x + d.x);
    atomicAdd(&colsum[2 * tid + 1], a.y + b.y + c.y + d.y);
  }
}

// ---------------- final: mean over nodes of out2 ----------------
__global__ __launch_bounds__(256) void final_reduce(const float* __restrict__ out2,
                                                    float* __restrict__ outsum, int Nn) {
  __shared__ float ls[32];
  if (threadIdx.x < 32) ls[threadIdx.x] = 0.f;
  __syncthreads();
  int d = threadIdx.x & 31, rl = threadIdx.x >> 5;
  float acc = 0.f;
  for (int n = blockIdx.x * 8 + rl; n < Nn; n += gridDim.x * 8)
    acc += out2[(size_t)n * 32 + d];
  atomicAdd(&ls[d], acc);
  __syncthreads();
  if (threadIdx.x < 32) atomicAdd(&outsum[threadIdx.x], ls[threadIdx.x]);
}

__global__ void finalize_k(const float* __restrict__ outsum, float* __restrict__ out, float invN) {
  int t = threadIdx.x;
  if (t < 32) out[t] = outsum[t] * invN;
}

// ---------------- launcher ----------------
extern "C" void kernel_launch(void* const* d_in, const int* in_sizes, int n_in,
                              void* d_out, int out_size, void* d_ws, size_t ws_size,
                              hipStream_t stream) {
  const float* x     = (const float*)d_in[0];
  const int*   src   = (const int*)d_in[1];
  const int*   dst   = (const int*)d_in[2];
  const float* W0    = (const float*)d_in[3];
  const float* al0   = (const float*)d_in[4];
  const float* ar0   = (const float*)d_in[5];
  const float* W1    = (const float*)d_in[6];
  const float* al1   = (const float*)d_in[7];
  const float* ar1   = (const float*)d_in[8];
  const float* resW1 = (const float*)d_in[9];
  const float* W2    = (const float*)d_in[10];
  const float* al2   = (const float*)d_in[11];
  const float* ar2   = (const float*)d_in[12];
  const float* resW2 = (const float*)d_in[13];
  const int N = in_sizes[0] / 64;   // 100000
  const int E = in_sizes[1];        // 1600000
  const float invN = 1.f / (float)N;
  const int Emax = E + 64;              // unpadded CSR + zeroed tail guard
  const int NB = (N + 255) >> 8;        // dst buckets of 256 nodes (391)
  const int P2B = 512;                  // histogram/scatter block count
  const int chunk = (((E + P2B - 1) / P2B) + 3) & ~3;  // multiple of 4 for int4 loads
  const int segN = NB * P2B;            // bucket-major segment table length
  const int nbB = (segN + 1023) / 1024; // scan blocks for segment table (196)

  char* p = (char*)d_ws;
  auto alloc = [&](size_t bytes) { char* r = p; p += (bytes + 255) & ~(size_t)255; return r; };

  // zero-initialized region (small: reduction accumulators only)
  char* zbase = p;
  float* colsumA = (float*)alloc(512);
  float* colsumB = (float*)alloc(512);
  float* outsum  = (float*)alloc(128);
  size_t zbytes = (size_t)(p - zbase);

  int* counts = (int*)alloc((size_t)4 * N);     // written by fscatter
  int* rsp    = (int*)alloc((size_t)4 * N);     // written by fscatter (unpadded row starts)
  int* bsumB  = (int*)alloc(1024);
  int* bhist  = (int*)alloc((size_t)4 * segN);  // per-(bucket,block) counts -> per-1024-block scan
  unsigned int* ebuf = (unsigned int*)alloc((size_t)4 * E);  // packed (src<<8)|(dst&255)
  int* csr_src = (int*)alloc((size_t)4 * Emax);
  unsigned char*  feat8 = (unsigned char*)alloc((size_t)N * 128);     // fp8 gather table
  unsigned short* vbf   = (unsigned short*)alloc((size_t)2 * N * 128);
  unsigned short* resh  = (unsigned short*)alloc((size_t)2 * N * 128);  // f16 residuals
  unsigned short* w0t = (unsigned short*)alloc((size_t)2 * 2 * 144 * 64);
  unsigned short* w1t = (unsigned short*)alloc((size_t)2 * 2 * 272 * 128);
  unsigned short* w2t = (unsigned short*)alloc((size_t)2 * 2 * 80 * 128);
  float* el4  = (float*)alloc((size_t)16 * N);
  float* er4  = (float*)alloc((size_t)16 * N);
  float* rnrm = (float*)alloc((size_t)4 * N);
  float* cmw1 = (float*)alloc(4 * 272);
  float* cmw2 = (float*)alloc(4 * 80);
  float* out2 = (float*)alloc((size_t)4 * N * 32);   // layer-2 output [N][32]

  hipMemsetAsync(zbase, 0, zbytes, stream);
  hipMemsetAsync(csr_src + E, 0, (size_t)4 * (Emax - E), stream);  // tail guard only

  // CSR build + weight pack
  const int packTot = 144 * 64 + 272 * 128 + 80 * 128;   // 54272
  const int packBlocks = (packTot + 255) / 256;          // 212
  hist_pack_k<<<P2B + packBlocks, 256, 0, stream>>>(dst, bhist, E, NB, chunk, P2B,
                                                    W0, al0, ar0, W1, al1, ar1, resW1,
                                                    W2, al2, ar2, resW2, w0t, w1t, w2t);
  pscan1<<<nbB, 256, 0, stream>>>(bhist, bsumB, segN);
  bscatter_k<<<P2B, 256, 0, stream>>>(src, dst, bhist, bsumB, ebuf, E, NB, chunk, nbB);
  fscatter_k<<<NB, 256, 0, stream>>>(ebuf, bhist, bsumB, csr_src, counts, rsp, E, NB, P2B, N, nbB);

  const int rowTiles = N / 16;                   // 6250
  const int gblocks = (rowTiles + 7) / 8;        // 4 waves x R=2 tiles = 8 tiles/block
  const int aggblocks = (N + 3) / 4;             // wave per node

  // Layer 0 (A = x fp32, no colmean fold): FULL-staged B (36.8KB)
  gemm_bf16<64, 144, 2, 128, 4, 144, true, false, true><<<gblocks, 256, 0, stream>>>(
      x, w0t, nullptr, feat8, el4, er4, nullptr, rowTiles);
  aggregate4<0><<<aggblocks, 256, 0, stream>>>(feat8, el4, er4, csr_src, rsp, counts, nullptr, vbf, rnrm, N);
  colsum_k<<<512, 256, 0, stream>>>(vbf, rnrm, colsumA, N);
  cmw_k<<<2, 256, 0, stream>>>(colsumA, w1t, cmw1, 128, 272, invN);

  // Layer 1 (A = vbf, colmean via cmw1): R20 two-barrier form (B = 136KB too big)
  gemm_bf16<128, 272, 2, 128, 4, 144, false, true, false><<<gblocks, 256, 0, stream>>>(
      vbf, w1t, cmw1, feat8, el4, er4, resh, rowTiles);
  aggregate4<1><<<aggblocks, 256, 0, stream>>>(feat8, el4, er4, csr_src, rsp, counts, resh, vbf, rnrm, N);
  colsum_k<<<512, 256, 0, stream>>>(vbf, rnrm, colsumB, N);
  cmw_k<<<1, 256, 0, stream>>>(colsumB, w2t, cmw2, 128, 80, invN);

  // Layer 2 (A = vbf, colmean via cmw2): FULL-staged B (40KB)
  gemm_bf16<128, 80, 2, 32, 1, 48, false, true, true><<<gblocks, 256, 0, stream>>>(
      vbf, w2t, cmw2, feat8, el4, er4, resh, rowTiles);
  aggregate1<<<aggblocks, 256, 0, stream>>>(feat8, el4, er4, csr_src, rsp, counts, resh, out2, N);
  final_reduce<<<512, 256, 0, stream>>>(out2, outsum, N);
  finalize_k<<<1, 64, 0, stream>>>(outsum, (float*)d_out, invN);
}